// Round 18
// baseline (142.895 us; speedup 1.0000x reference)
//
#include <hip/hip_runtime.h>
#include <hip/hip_bf16.h>

typedef __bf16  bf16x8 __attribute__((ext_vector_type(8)));
typedef __bf16  bf16x4 __attribute__((ext_vector_type(4)));
typedef __bf16  bf16x2 __attribute__((ext_vector_type(2)));
typedef float   f32x4  __attribute__((ext_vector_type(4)));
typedef float   f32x16 __attribute__((ext_vector_type(16)));
typedef unsigned u32x4 __attribute__((ext_vector_type(4)));

#define MFMA16(a,b,c) __builtin_amdgcn_mfma_f32_16x16x32_bf16(a,b,c,0,0,0)
#define MFMA32(a,b,c) __builtin_amdgcn_mfma_f32_32x32x16_bf16(a,b,c,0,0,0)

// B=2, T=2048, D=1024, H=16, Dh=64

// ---------------- cast x (fp32 -> bf16), 4 elems/thread ----------------
struct bf4 { __hip_bfloat16 a,b,c,d; };

__global__ __launch_bounds__(256) void cast_f32_bf16(const float* __restrict__ in,
                                                     __hip_bfloat16* __restrict__ out,
                                                     int n4) {
  int i = blockIdx.x * 256 + threadIdx.x;
  if (i >= n4) return;
  float4 v = ((const float4*)in)[i];
  bf4 o { __float2bfloat16(v.x), __float2bfloat16(v.y),
          __float2bfloat16(v.z), __float2bfloat16(v.w) };
  ((bf4*)out)[i] = o;
}

// ------------- transpose + cast: W[R][C] fp32 -> WT[C][R] bf16 -------------
__global__ __launch_bounds__(256) void transpose_cast(const float* __restrict__ W,
                                                      __hip_bfloat16* __restrict__ WT,
                                                      int R, int C) {
  __shared__ float tile[32][33];
  int c0 = blockIdx.x * 32, r0 = blockIdx.y * 32;
  int tx = threadIdx.x & 31, ty = threadIdx.x >> 5;   // 32 x 8
  #pragma unroll
  for (int i = 0; i < 32; i += 8)
    tile[ty + i][tx] = W[(size_t)(r0 + ty + i) * C + c0 + tx];
  __syncthreads();
  #pragma unroll
  for (int i = 0; i < 32; i += 8)
    WT[(size_t)(c0 + ty + i) * R + r0 + tx] = __float2bfloat16(tile[tx][ty + i]);
}

// ------------- GEMM: C[M][N] = A[M][K] * BT[N][K]^T  (bf16 in, OutT out) -------------
// 128x128 tile, BK=32, double-buffered LDS with COUNTED vmcnt pipeline (proven R10/R15):
// STAGE(next) -> s_waitcnt vmcnt(4) -> s_barrier -> compute(cur) -> s_barrier.
// XOR slot-swizzle both sides.
template <typename OutT>
__global__ __launch_bounds__(256) void gemm_bt(const __hip_bfloat16* __restrict__ A,
                                               const __hip_bfloat16* __restrict__ BT,
                                               OutT* __restrict__ C,
                                               int M, int N, int K) {
  __shared__ __hip_bfloat16 As[2][128][32];
  __shared__ __hip_bfloat16 Bs[2][128][32];
  int tid  = threadIdx.x;
  int lane = tid & 63, wid = tid >> 6;
  int wm = wid >> 1, wn = wid & 1;
  int rowBase = blockIdx.y * 128;
  int colBase = blockIdx.x * 128;
  int lr = lane & 15, lg = lane >> 4;

  f32x4 acc[4][4];
  #pragma unroll
  for (int i = 0; i < 4; ++i)
    #pragma unroll
    for (int j = 0; j < 4; ++j) acc[i][j] = f32x4{0.f,0.f,0.f,0.f};

  int nt = K >> 5;

#define GSTAGE(buf, kt)                                                                 \
  do {                                                                                  \
    int k0_ = (kt) << 5;                                                                \
    _Pragma("unroll")                                                                   \
    for (int p = 0; p < 2; ++p) {                                                       \
      int idx = p * 256 + tid;                                                          \
      int r_ = idx >> 2, sl_ = idx & 3;                                                 \
      __builtin_amdgcn_global_load_lds(                                                 \
        (const __attribute__((address_space(1))) unsigned int*)                         \
          &A[(size_t)(rowBase + r_) * K + k0_ + ((sl_ ^ (r_ & 3)) * 8)],                \
        (__attribute__((address_space(3))) unsigned int*)&As[buf][r_][sl_ * 8], 16, 0, 0);\
      __builtin_amdgcn_global_load_lds(                                                 \
        (const __attribute__((address_space(1))) unsigned int*)                         \
          &BT[(size_t)(colBase + r_) * K + k0_ + ((sl_ ^ (r_ & 3)) * 8)],               \
        (__attribute__((address_space(3))) unsigned int*)&Bs[buf][r_][sl_ * 8], 16, 0, 0);\
    }                                                                                   \
  } while (0)

  GSTAGE(0, 0);
  for (int t = 0; t < nt; ++t) {
    int cur = t & 1;
    if (t + 1 < nt) {
      GSTAGE(cur ^ 1, t + 1);
      asm volatile("s_waitcnt vmcnt(4)" ::: "memory");   // tile t landed (own wave)
    } else {
      asm volatile("s_waitcnt vmcnt(0)" ::: "memory");
    }
    __builtin_amdgcn_s_barrier();                        // all waves' tile t landed
    __builtin_amdgcn_sched_barrier(0);

    bf16x8 af[4], bfr[4];
    #pragma unroll
    for (int mf = 0; mf < 4; ++mf) {
      int row = wm*64 + mf*16 + lr;
      af[mf]  = *(const bf16x8*)&As[cur][row][((lg ^ (lr & 3)) * 8)];
    }
    #pragma unroll
    for (int nf = 0; nf < 4; ++nf) {
      int row = wn*64 + nf*16 + lr;
      bfr[nf] = *(const bf16x8*)&Bs[cur][row][((lg ^ (lr & 3)) * 8)];
    }
    #pragma unroll
    for (int mf = 0; mf < 4; ++mf)
      #pragma unroll
      for (int nf = 0; nf < 4; ++nf)
        acc[mf][nf] = MFMA16(af[mf], bfr[nf], acc[mf][nf]);

    __builtin_amdgcn_s_barrier();                        // readers done before overwrite
  }
#undef GSTAGE

  #pragma unroll
  for (int mf = 0; mf < 4; ++mf)
    #pragma unroll
    for (int nf = 0; nf < 4; ++nf)
      #pragma unroll
      for (int r = 0; r < 4; ++r) {
        int row = rowBase + wm*64 + mf*16 + lg*4 + r;
        int col = colBase + wn*64 + nf*16 + lr;
        float v = acc[mf][nf][r];
        if constexpr (sizeof(OutT) == 2) C[(size_t)row * N + col] = __float2bfloat16(v);
        else                             C[(size_t)row * N + col] = v;
      }
}

// ------------- sin/cos table: tbl[t*32+i] = {sin,cos}(t * 10000^(-i/32)) -------------
__global__ __launch_bounds__(256) void build_sincos(float2* __restrict__ tbl) {
  int idx = blockIdx.x * 256 + threadIdx.x;   // 65536 = 2048 t x 32 i
  int i = idx & 31, t = idx >> 5;
  float theta = expf(-9.210340371976184f * (float)i * 0.03125f);  // 10000^(-i/32)
  float sn, cs;
  sincosf((float)t * theta, &sn, &cs);
  tbl[idx] = float2{sn, cs};
}

// ------------- RoPE (vectorized, 8 elems/thread): qkv -> Qb (pre-scaled), Kb -------------
__global__ __launch_bounds__(256) void rope_qk(const __hip_bfloat16* __restrict__ qkv,
                                               const float2* __restrict__ tbl,
                                               __hip_bfloat16* __restrict__ Qb,
                                               __hip_bfloat16* __restrict__ Kb) {
  int idx = blockIdx.x * 256 + threadIdx.x;   // [0, 2^18): 4 i8 | 16 h | 2048 t | 2 b
  int i8 = idx & 3;
  int h  = (idx >> 2) & 15;
  int t  = (idx >> 6) & 2047;
  int b  = idx >> 17;
  int i0 = i8 * 8;
  size_t row = (size_t)(b * 2048 + t) * 3072;
  bf16x8 q1 = *(const bf16x8*)&qkv[row + h*64 + i0];
  bf16x8 q2 = *(const bf16x8*)&qkv[row + h*64 + 32 + i0];
  bf16x8 k1 = *(const bf16x8*)&qkv[row + 1024 + h*64 + i0];
  bf16x8 k2 = *(const bf16x8*)&qkv[row + 1024 + h*64 + 32 + i0];
  const float2* tb = &tbl[(t << 5) + i0];

  const float QS = 0.18033688011112042f;  // (1/8) * log2(e)
  bf16x8 qo1, qo2, ko1, ko2;
  #pragma unroll
  for (int e = 0; e < 8; ++e) {
    float2 sc = tb[e];
    float sn = sc.x, cs = sc.y;
    float a = (float)q1[e], bb = (float)q2[e];
    float c = (float)k1[e], dd = (float)k2[e];
    qo1[e] = (__bf16)(( a*cs + bb*sn) * QS);
    qo2[e] = (__bf16)((-a*sn + bb*cs) * QS);
    ko1[e] = (__bf16)( c*cs + dd*sn);
    ko2[e] = (__bf16)(-c*sn + dd*cs);
  }
  size_t qkbase = ((size_t)(b*16 + h) * 2048 + t) * 64;
  *(bf16x8*)&Qb[qkbase + i0]      = qo1;
  *(bf16x8*)&Qb[qkbase + 32 + i0] = qo2;
  *(bf16x8*)&Kb[qkbase + i0]      = ko1;
  *(bf16x8*)&Kb[qkbase + 32 + i0] = ko2;
}

// ------------- V transpose: qkv[b*T+t][2048 + h*64 + d] -> Vt[(bh*64+d)][t] -------------
__global__ __launch_bounds__(256) void v_transpose(const __hip_bfloat16* __restrict__ qkv,
                                                   __hip_bfloat16* __restrict__ Vt) {
  __shared__ __hip_bfloat16 tile[64][66];
  int blk = blockIdx.x;        // 32 tblk | 16 h | 2 b = 1024
  int tb = blk & 31, hh = (blk >> 5) & 15, bb = blk >> 9;
  int t0 = tb * 64;
  int tid = threadIdx.x;
  int row = tid >> 2, dc = (tid & 3) * 16;
  const __hip_bfloat16* src = qkv + (size_t)(bb*2048 + t0 + row) * 3072 + 2048 + hh*64 + dc;
  *(bf16x8*)&tile[row][dc]     = *(const bf16x8*)&src[0];
  *(bf16x8*)&tile[row][dc + 8] = *(const bf16x8*)&src[8];
  __syncthreads();
  int d = tid >> 2, tc = (tid & 3) * 16;
  __hip_bfloat16 outv[16];
  #pragma unroll
  for (int k = 0; k < 16; ++k) outv[k] = tile[tc + k][d];
  __hip_bfloat16* dst = Vt + ((size_t)(bb*16 + hh) * 64 + d) * 2048 + t0 + tc;
  *(bf16x8*)&dst[0] = *(bf16x8*)&outv[0];
  *(bf16x8*)&dst[8] = *(bf16x8*)&outv[8];
}

// pack two floats to one dword of 2 bf16 (compiler emits v_cvt_pk_bf16_f32)
__device__ __forceinline__ unsigned pk2(float lo, float hi_) {
  bf16x2 t; t[0] = (__bf16)lo; t[1] = (__bf16)hi_;
  return __builtin_bit_cast(unsigned, t);
}

// ------------- Split-KV flash attention, LDS-shared K/V, 8 waves/block, KVBLK=64 -------------
// R15 structure with KVBLK 32->64: 8 iterations per chunk instead of 16 (half the
// barrier pairs), each iteration stages a 64-kv K tile (8KB) + 64-col V tile (8KB)
// and computes TWO 32-kv subtiles back-to-back. Depth-1 counted-vmcnt pipeline
// (proven R10/R12/R15): ASTAGE(next) -> vmcnt(2) -> barrier -> compute -> barrier.
// Unified K/V LDS layout: [64 rows][8 slots of 8 bf16], slot = col_granule ^ (row&7)
// (both-sides involution: pre-swizzled global source + swizzled read).
// Jobs/Opart/combine indexing identical to the passing R15 version.
__global__ __launch_bounds__(512) void attn_chunk(const __hip_bfloat16* __restrict__ Qb,
                                                  const __hip_bfloat16* __restrict__ Kb,
                                                  const __hip_bfloat16* __restrict__ Vt,
                                                  __hip_bfloat16* __restrict__ Opart,
                                                  float* __restrict__ sbuf) {
  __shared__ __hip_bfloat16 Ks[2][4096];   // [64 kv][8 slots of 8 bf16], swizzled
  __shared__ __hip_bfloat16 Vs[2][4096];   // [64 d ][8 slots of 8 bf16], swizzled
  int tid = threadIdx.x;
  int wid = tid >> 6, lane = tid & 63;
  int ql = lane & 31, hi = lane >> 5;

  int bid = blockIdx.x;
  int bh, c, jbase, lenmax; bool diag;
  if (bid < 384) {                       // full chunks (len32 16)
    bh = bid / 12; int pr = bid % 12;
    if (pr < 6)       { c = 0; jbase = 16 + 8*pr; }
    else if (pr < 10) { c = 1; jbase = 32 + 8*(pr-6); }
    else              { c = 2; jbase = 48 + 8*(pr-10); }
    lenmax = 16; diag = false;
  } else {                               // diagonal chunks; longer halves first (LPT)
    int e = bid - 384;
    int hh = (e < 128) ? 1 : 0;
    int e2 = e & 127;
    bh = e2 >> 2; c = e2 & 3;
    jbase = 16*c + 8*hh; lenmax = 8*hh + 8; diag = true;
  }
  int j = jbase + wid;
  int len32 = diag ? ((j & 15) + 1) : 16;
  int q0 = j * 32, t0 = c * 512;
  int lenmax64 = lenmax >> 1;            // 8 (full, diag-hi) or 4 (diag-lo)
  int jobid;
  if (!diag) jobid = (c == 0) ? (j - 16) : ((c == 1) ? (j + 16) : (j + 32));
  else       jobid = 96 + ((15 - (j & 15)) << 2) + c;
  int job = jobid * 32 + bh;

  const __hip_bfloat16* Qp = Qb + (size_t)bh * 2048 * 64;
  const __hip_bfloat16* Kp = Kb + (size_t)bh * 2048 * 64;
  const __hip_bfloat16* Vp = Vt + (size_t)bh * 64 * 2048;

  bf16x8 qf[4];
  #pragma unroll
  for (int cc = 0; cc < 4; ++cc)
    qf[cc] = *(const bf16x8*)&Qp[(size_t)(q0 + ql) * 64 + cc*16 + hi*8];

  f32x16 o0, o1;
  #pragma unroll
  for (int r = 0; r < 16; ++r) { o0[r] = 0.f; o1[r] = 0.f; }
  float s = 0.f;

  // staging thread roles: each of 512 threads stages 1 K granule + 1 V granule
  int gr = tid >> 3, gsl = tid & 7;      // granule row (0..63), slot (0..7)
  int gsrc = gsl ^ (gr & 7);             // source column granule (involution)

#define ASTAGE(buf, it_)                                                                \
  do {                                                                                  \
    int kvb_ = t0 + (it_) * 64;                                                         \
    __builtin_amdgcn_global_load_lds(                                                   \
      (const __attribute__((address_space(1))) unsigned int*)                           \
        &Kp[(size_t)(kvb_ + gr) * 64 + gsrc * 8],                                       \
      (__attribute__((address_space(3))) unsigned int*)&Ks[buf][tid * 8], 16, 0, 0);    \
    __builtin_amdgcn_global_load_lds(                                                   \
      (const __attribute__((address_space(1))) unsigned int*)                           \
        &Vp[(size_t)gr * 2048 + kvb_ + gsrc * 8],                                       \
      (__attribute__((address_space(3))) unsigned int*)&Vs[buf][tid * 8], 16, 0, 0);    \
  } while (0)

  ASTAGE(0, 0);
  for (int it = 0; it < lenmax64; ++it) {
    int cur = it & 1;
    if (it + 1 < lenmax64) {
      ASTAGE(cur ^ 1, it + 1);
      asm volatile("s_waitcnt vmcnt(2)" ::: "memory");   // tile it landed (own wave)
    } else {
      asm volatile("s_waitcnt vmcnt(0)" ::: "memory");
    }
    __builtin_amdgcn_s_barrier();                        // all waves' tile it landed
    __builtin_amdgcn_sched_barrier(0);

    #pragma unroll
    for (int ss = 0; ss < 2; ++ss) {
      int s32 = it * 2 + ss;
      if (s32 < len32) {
        int kv0 = t0 + s32 * 32;
        bf16x8 kf[4], vf[4];
        #pragma unroll
        for (int cc = 0; cc < 4; ++cc) {
          int krow = ss*32 + ql;
          kf[cc] = *(const bf16x8*)&Ks[cur][(krow*8 + ((cc*2 + hi) ^ (krow & 7))) * 8];
        }
        #pragma unroll
        for (int g = 0; g < 2; ++g)
          #pragma unroll
          for (int cc = 0; cc < 2; ++cc) {
            int d_ = g*32 + ql;
            int tc_ = ss*4 + cc*2 + hi;
            vf[g*2 + cc] = *(const bf16x8*)&Vs[cur][(d_*8 + (tc_ ^ (d_ & 7))) * 8];
          }

        f32x16 st;
        #pragma unroll
        for (int r = 0; r < 16; ++r) st[r] = 0.f;
        #pragma unroll
        for (int cc = 0; cc < 4; ++cc) st = MFMA32(kf[cc], qf[cc], st);
        // st is in log2 units (Q pre-scaled by 0.125*log2e)

        if (diag && s32 == len32 - 1) {  // diagonal subtile: causal mask
          #pragma unroll
          for (int r = 0; r < 16; ++r) {
            int kv = kv0 + (r & 3) + 8*(r >> 2) + 4*hi;
            if (kv > q0 + ql) st[r] = -1e30f;
          }
        }

        float p[16]; float ps = 0.f;
        #pragma unroll
        for (int r = 0; r < 16; ++r) { p[r] = exp2f(st[r]); ps += p[r]; }
        ps += __shfl_xor(ps, 32);
        s += ps;

        // P^T B-frag pack: pack own pairs to bf16 dwords, exchange cross-half dwords
        bf16x8 pb[2];
        #pragma unroll
        for (int cc = 0; cc < 2; ++cc) {
          unsigned w0 = pk2(p[cc*8+0], p[cc*8+1]);
          unsigned w1 = pk2(p[cc*8+2], p[cc*8+3]);
          unsigned w2 = pk2(p[cc*8+4], p[cc*8+5]);
          unsigned w3 = pk2(p[cc*8+6], p[cc*8+7]);
          unsigned r0 = __shfl_xor(hi ? w0 : w2, 32);
          unsigned r1 = __shfl_xor(hi ? w1 : w3, 32);
          u32x4 pw;
          pw[0] = hi ? r0 : w0;
          pw[1] = hi ? r1 : w1;
          pw[2] = hi ? w2 : r0;
          pw[3] = hi ? w3 : r1;
          pb[cc] = __builtin_bit_cast(bf16x8, pw);
        }

        o0 = MFMA32(vf[0], pb[0], o0);
        o0 = MFMA32(vf[1], pb[1], o0);
        o1 = MFMA32(vf[2], pb[0], o1);
        o1 = MFMA32(vf[3], pb[1], o1);
      }
    }
    __builtin_amdgcn_s_barrier();                        // readers done before overwrite
  }
#undef ASTAGE

  // write UNNORMALIZED partial: Opart[job][ql][d] (bf16, [32][64] per job), sbuf[job][ql]=s
  __hip_bfloat16* Op = Opart + (size_t)job * 2048 + ql * 64;
  #pragma unroll
  for (int rr = 0; rr < 4; ++rr) {
    bf16x4 w;
    #pragma unroll
    for (int e = 0; e < 4; ++e) w[e] = (__bf16)o0[rr*4 + e];
    *(bf16x4*)&Op[8*rr + 4*hi] = w;
  }
  #pragma unroll
  for (int rr = 0; rr < 4; ++rr) {
    bf16x4 w;
    #pragma unroll
    for (int e = 0; e < 4; ++e) w[e] = (__bf16)o1[rr*4 + e];
    *(bf16x4*)&Op[32 + 8*rr + 4*hi] = w;
  }
  if (hi == 0) sbuf[(size_t)job * 32 + ql] = s;
}

// ------------- combine partials: per (b,h,j) sum <=4 chunks, normalize, write Ob -------------
__global__ __launch_bounds__(64) void attn_combine(const __hip_bfloat16* __restrict__ Opart,
                                                   const float* __restrict__ sbuf,
                                                   __hip_bfloat16* __restrict__ Ob) {
  int bid2 = blockIdx.x;              // 2048 = 64 j x 32 bh
  int j = bid2 >> 5, bh = bid2 & 31;
  int h = bh & 15, b = bh >> 4;
  int tid = threadIdx.x, ql = tid & 31, half = tid >> 5;
  int nc = (j >> 4) + 1;

  int gs[4];
  const int Sseg[3] = {0, 48, 80};
  #pragma unroll
  for (int i = 0; i < 3; ++i)
    if (i < nc - 1) gs[i] = (Sseg[i] + j - 16*(i+1)) * 32 + bh;
  gs[nc-1] = (96 + 4*(15 - (j & 15)) + (j >> 4)) * 32 + bh;

  float Ssum = 0.f;
  #pragma unroll
  for (int i = 0; i < 4; ++i)
    if (i < nc) Ssum += sbuf[(size_t)gs[i]*32 + ql];

  float acc[32];
  #pragma unroll
  for (int e = 0; e < 32; ++e) acc[e] = 0.f;
  #pragma unroll
  for (int i = 0; i < 4; ++i)
    if (i < nc) {
      const bf16x8* src = (const bf16x8*)(Opart + (size_t)gs[i]*2048 + ql*64 + half*32);
      #pragma unroll
      for (int q4 = 0; q4 < 4; ++q4) {
        bf16x8 v = src[q4];
        #pragma unroll
        for (int e = 0; e < 8; ++e) acc[q4*8 + e] += (float)v[e];
      }
    }

  float inv = 1.f / Ssum;
  size_t row = (size_t)b * 2048 + j*32 + ql;
  __hip_bfloat16* dst = Ob + row * 1024 + h*64 + half*32;
  #pragma unroll
  for (int q4 = 0; q4 < 4; ++q4) {
    bf16x8 w;
    #pragma unroll
    for (int e = 0; e < 8; ++e) w[e] = (__bf16)(acc[q4*8 + e] * inv);
    *(bf16x8*)&dst[q4*8] = w;
  }
}

// ---------------------------------------------------------------------------
extern "C" void kernel_launch(void* const* d_in, const int* in_sizes, int n_in,
                              void* d_out, int out_size, void* d_ws, size_t ws_size,
                              hipStream_t stream) {
  const float* x     = (const float*)d_in[0];
  // d_in[1] = mask (fixed causal triu) — implemented analytically
  const float* Wqkv  = (const float*)d_in[2];
  const float* Wproj = (const float*)d_in[3];
  float* out = (float*)d_out;

  char* ws = (char*)d_ws;
  const size_t MB = 1024 * 1024;
  __hip_bfloat16* xb  = (__hip_bfloat16*)(ws);            //  8 MB  [4096][1024]
  __hip_bfloat16* Wqt = (__hip_bfloat16*)(ws +  8*MB);    //  6 MB  [3072][1024]
  __hip_bfloat16* Wpt = (__hip_bfloat16*)(ws + 14*MB);    //  2 MB  [1024][1024]
  __hip_bfloat16* qkv = (__hip_bfloat16*)(ws + 16*MB);    // 24 MB  [4096][3072]
  __hip_bfloat16* Qb  = (__hip_bfloat16*)(ws + 40*MB);    //  8 MB  [B,H,T,64]
  __hip_bfloat16* Kb  = (__hip_bfloat16*)(ws + 48*MB);    //  8 MB
  __hip_bfloat16* Vt  = (__hip_bfloat16*)(ws + 56*MB);    //  8 MB  [B,H,64,T]
  __hip_bfloat16* Ob  = (__hip_bfloat16*)(ws + 64*MB);    //  8 MB  [4096][1024]
  // attn partials overlay the dead qkv region (qkv unused after rope/v_transpose)
  __hip_bfloat16* Opart = (__hip_bfloat16*)(ws + 16*MB);  // 20 MB  [5120][32][64]
  float*          sbuf  = (float*)(ws + 36*MB);           // 640KB  [5120][32]
  // sin/cos table overlays the dead Wqt region (Wqt unused after first gemm)
  float2*         sctbl = (float2*)(ws + 8*MB);           // 512KB  [2048*32]

  cast_f32_bf16<<<4096, 256, 0, stream>>>(x, xb, 1048576);
  transpose_cast<<<dim3(96, 32), 256, 0, stream>>>(Wqkv, Wqt, 1024, 3072);
  transpose_cast<<<dim3(32, 32), 256, 0, stream>>>(Wproj, Wpt, 1024, 1024);
  gemm_bt<__hip_bfloat16><<<dim3(24, 32), 256, 0, stream>>>(xb, Wqt, qkv, 4096, 3072, 1024);
  build_sincos<<<256, 256, 0, stream>>>(sctbl);
  rope_qk<<<1024, 256, 0, stream>>>(qkv, sctbl, Qb, Kb);
  v_transpose<<<1024, 256, 0, stream>>>(qkv, Vt);
  attn_chunk<<<640, 512, 0, stream>>>(Qb, Kb, Vt, Opart, sbuf);
  attn_combine<<<2048, 64, 0, stream>>>(Opart, sbuf, Ob);
  gemm_bt<float><<<dim3(8, 32), 256, 0, stream>>>(Ob, Wpt, out, 4096, 1024, 1024);
}

// Round 19
// 137.675 us; speedup vs baseline: 1.0379x; 1.0379x over previous
//
#include <hip/hip_runtime.h>
#include <hip/hip_bf16.h>

typedef __bf16  bf16x8 __attribute__((ext_vector_type(8)));
typedef __bf16  bf16x4 __attribute__((ext_vector_type(4)));
typedef __bf16  bf16x2 __attribute__((ext_vector_type(2)));
typedef float   f32x4  __attribute__((ext_vector_type(4)));
typedef float   f32x16 __attribute__((ext_vector_type(16)));
typedef unsigned u32x4 __attribute__((ext_vector_type(4)));

#define MFMA16(a,b,c) __builtin_amdgcn_mfma_f32_16x16x32_bf16(a,b,c,0,0,0)
#define MFMA32(a,b,c) __builtin_amdgcn_mfma_f32_32x32x16_bf16(a,b,c,0,0,0)

// B=2, T=2048, D=1024, H=16, Dh=64

// ---------------- cast x (fp32 -> bf16), 4 elems/thread ----------------
struct bf4 { __hip_bfloat16 a,b,c,d; };

__global__ __launch_bounds__(256) void cast_f32_bf16(const float* __restrict__ in,
                                                     __hip_bfloat16* __restrict__ out,
                                                     int n4) {
  int i = blockIdx.x * 256 + threadIdx.x;
  if (i >= n4) return;
  float4 v = ((const float4*)in)[i];
  bf4 o { __float2bfloat16(v.x), __float2bfloat16(v.y),
          __float2bfloat16(v.z), __float2bfloat16(v.w) };
  ((bf4*)out)[i] = o;
}

// ------------- transpose + cast: W[R][C] fp32 -> WT[C][R] bf16 -------------
__global__ __launch_bounds__(256) void transpose_cast(const float* __restrict__ W,
                                                      __hip_bfloat16* __restrict__ WT,
                                                      int R, int C) {
  __shared__ float tile[32][33];
  int c0 = blockIdx.x * 32, r0 = blockIdx.y * 32;
  int tx = threadIdx.x & 31, ty = threadIdx.x >> 5;   // 32 x 8
  #pragma unroll
  for (int i = 0; i < 32; i += 8)
    tile[ty + i][tx] = W[(size_t)(r0 + ty + i) * C + c0 + tx];
  __syncthreads();
  #pragma unroll
  for (int i = 0; i < 32; i += 8)
    WT[(size_t)(c0 + ty + i) * R + r0 + tx] = __float2bfloat16(tile[tx][ty + i]);
}

// ------------- GEMM: C[M][N] = A[M][K] * BT[N][K]^T  (bf16 in, OutT out) -------------
// 128x128 tile, BK=32, double-buffered LDS with COUNTED vmcnt pipeline (proven R10/R15):
// STAGE(next) -> s_waitcnt vmcnt(4) -> s_barrier -> compute(cur) -> s_barrier.
// XOR slot-swizzle both sides.
template <typename OutT>
__global__ __launch_bounds__(256) void gemm_bt(const __hip_bfloat16* __restrict__ A,
                                               const __hip_bfloat16* __restrict__ BT,
                                               OutT* __restrict__ C,
                                               int M, int N, int K) {
  __shared__ __hip_bfloat16 As[2][128][32];
  __shared__ __hip_bfloat16 Bs[2][128][32];
  int tid  = threadIdx.x;
  int lane = tid & 63, wid = tid >> 6;
  int wm = wid >> 1, wn = wid & 1;
  int rowBase = blockIdx.y * 128;
  int colBase = blockIdx.x * 128;
  int lr = lane & 15, lg = lane >> 4;

  f32x4 acc[4][4];
  #pragma unroll
  for (int i = 0; i < 4; ++i)
    #pragma unroll
    for (int j = 0; j < 4; ++j) acc[i][j] = f32x4{0.f,0.f,0.f,0.f};

  int nt = K >> 5;

#define GSTAGE(buf, kt)                                                                 \
  do {                                                                                  \
    int k0_ = (kt) << 5;                                                                \
    _Pragma("unroll")                                                                   \
    for (int p = 0; p < 2; ++p) {                                                       \
      int idx = p * 256 + tid;                                                          \
      int r_ = idx >> 2, sl_ = idx & 3;                                                 \
      __builtin_amdgcn_global_load_lds(                                                 \
        (const __attribute__((address_space(1))) unsigned int*)                         \
          &A[(size_t)(rowBase + r_) * K + k0_ + ((sl_ ^ (r_ & 3)) * 8)],                \
        (__attribute__((address_space(3))) unsigned int*)&As[buf][r_][sl_ * 8], 16, 0, 0);\
      __builtin_amdgcn_global_load_lds(                                                 \
        (const __attribute__((address_space(1))) unsigned int*)                         \
          &BT[(size_t)(colBase + r_) * K + k0_ + ((sl_ ^ (r_ & 3)) * 8)],               \
        (__attribute__((address_space(3))) unsigned int*)&Bs[buf][r_][sl_ * 8], 16, 0, 0);\
    }                                                                                   \
  } while (0)

  GSTAGE(0, 0);
  for (int t = 0; t < nt; ++t) {
    int cur = t & 1;
    if (t + 1 < nt) {
      GSTAGE(cur ^ 1, t + 1);
      asm volatile("s_waitcnt vmcnt(4)" ::: "memory");   // tile t landed (own wave)
    } else {
      asm volatile("s_waitcnt vmcnt(0)" ::: "memory");
    }
    __builtin_amdgcn_s_barrier();                        // all waves' tile t landed
    __builtin_amdgcn_sched_barrier(0);

    bf16x8 af[4], bfr[4];
    #pragma unroll
    for (int mf = 0; mf < 4; ++mf) {
      int row = wm*64 + mf*16 + lr;
      af[mf]  = *(const bf16x8*)&As[cur][row][((lg ^ (lr & 3)) * 8)];
    }
    #pragma unroll
    for (int nf = 0; nf < 4; ++nf) {
      int row = wn*64 + nf*16 + lr;
      bfr[nf] = *(const bf16x8*)&Bs[cur][row][((lg ^ (lr & 3)) * 8)];
    }
    #pragma unroll
    for (int mf = 0; mf < 4; ++mf)
      #pragma unroll
      for (int nf = 0; nf < 4; ++nf)
        acc[mf][nf] = MFMA16(af[mf], bfr[nf], acc[mf][nf]);

    __builtin_amdgcn_s_barrier();                        // readers done before overwrite
  }
#undef GSTAGE

  #pragma unroll
  for (int mf = 0; mf < 4; ++mf)
    #pragma unroll
    for (int nf = 0; nf < 4; ++nf)
      #pragma unroll
      for (int r = 0; r < 4; ++r) {
        int row = rowBase + wm*64 + mf*16 + lg*4 + r;
        int col = colBase + wn*64 + nf*16 + lr;
        float v = acc[mf][nf][r];
        if constexpr (sizeof(OutT) == 2) C[(size_t)row * N + col] = __float2bfloat16(v);
        else                             C[(size_t)row * N + col] = v;
      }
}

// ------------- sin/cos table: tbl[t*32+i] = {sin,cos}(t * 10000^(-i/32)) -------------
__global__ __launch_bounds__(256) void build_sincos(float2* __restrict__ tbl) {
  int idx = blockIdx.x * 256 + threadIdx.x;   // 65536 = 2048 t x 32 i
  int i = idx & 31, t = idx >> 5;
  float theta = expf(-9.210340371976184f * (float)i * 0.03125f);  // 10000^(-i/32)
  float sn, cs;
  sincosf((float)t * theta, &sn, &cs);
  tbl[idx] = float2{sn, cs};
}

// ------------- RoPE (vectorized, 8 elems/thread): qkv -> Qb (pre-scaled), Kb -------------
__global__ __launch_bounds__(256) void rope_qk(const __hip_bfloat16* __restrict__ qkv,
                                               const float2* __restrict__ tbl,
                                               __hip_bfloat16* __restrict__ Qb,
                                               __hip_bfloat16* __restrict__ Kb) {
  int idx = blockIdx.x * 256 + threadIdx.x;   // [0, 2^18): 4 i8 | 16 h | 2048 t | 2 b
  int i8 = idx & 3;
  int h  = (idx >> 2) & 15;
  int t  = (idx >> 6) & 2047;
  int b  = idx >> 17;
  int i0 = i8 * 8;
  size_t row = (size_t)(b * 2048 + t) * 3072;
  bf16x8 q1 = *(const bf16x8*)&qkv[row + h*64 + i0];
  bf16x8 q2 = *(const bf16x8*)&qkv[row + h*64 + 32 + i0];
  bf16x8 k1 = *(const bf16x8*)&qkv[row + 1024 + h*64 + i0];
  bf16x8 k2 = *(const bf16x8*)&qkv[row + 1024 + h*64 + 32 + i0];
  const float2* tb = &tbl[(t << 5) + i0];

  const float QS = 0.18033688011112042f;  // (1/8) * log2(e)
  bf16x8 qo1, qo2, ko1, ko2;
  #pragma unroll
  for (int e = 0; e < 8; ++e) {
    float2 sc = tb[e];
    float sn = sc.x, cs = sc.y;
    float a = (float)q1[e], bb = (float)q2[e];
    float c = (float)k1[e], dd = (float)k2[e];
    qo1[e] = (__bf16)(( a*cs + bb*sn) * QS);
    qo2[e] = (__bf16)((-a*sn + bb*cs) * QS);
    ko1[e] = (__bf16)( c*cs + dd*sn);
    ko2[e] = (__bf16)(-c*sn + dd*cs);
  }
  size_t qkbase = ((size_t)(b*16 + h) * 2048 + t) * 64;
  *(bf16x8*)&Qb[qkbase + i0]      = qo1;
  *(bf16x8*)&Qb[qkbase + 32 + i0] = qo2;
  *(bf16x8*)&Kb[qkbase + i0]      = ko1;
  *(bf16x8*)&Kb[qkbase + 32 + i0] = ko2;
}

// ------------- V transpose: qkv[b*T+t][2048 + h*64 + d] -> Vt[(bh*64+d)][t] -------------
__global__ __launch_bounds__(256) void v_transpose(const __hip_bfloat16* __restrict__ qkv,
                                                   __hip_bfloat16* __restrict__ Vt) {
  __shared__ __hip_bfloat16 tile[64][66];
  int blk = blockIdx.x;        // 32 tblk | 16 h | 2 b = 1024
  int tb = blk & 31, hh = (blk >> 5) & 15, bb = blk >> 9;
  int t0 = tb * 64;
  int tid = threadIdx.x;
  int row = tid >> 2, dc = (tid & 3) * 16;
  const __hip_bfloat16* src = qkv + (size_t)(bb*2048 + t0 + row) * 3072 + 2048 + hh*64 + dc;
  *(bf16x8*)&tile[row][dc]     = *(const bf16x8*)&src[0];
  *(bf16x8*)&tile[row][dc + 8] = *(const bf16x8*)&src[8];
  __syncthreads();
  int d = tid >> 2, tc = (tid & 3) * 16;
  __hip_bfloat16 outv[16];
  #pragma unroll
  for (int k = 0; k < 16; ++k) outv[k] = tile[tc + k][d];
  __hip_bfloat16* dst = Vt + ((size_t)(bb*16 + hh) * 64 + d) * 2048 + t0 + tc;
  *(bf16x8*)&dst[0] = *(bf16x8*)&outv[0];
  *(bf16x8*)&dst[8] = *(bf16x8*)&outv[8];
}

// pack two floats to one dword of 2 bf16 (compiler emits v_cvt_pk_bf16_f32)
__device__ __forceinline__ unsigned pk2(float lo, float hi_) {
  bf16x2 t; t[0] = (__bf16)lo; t[1] = (__bf16)hi_;
  return __builtin_bit_cast(unsigned, t);
}

// ------------- Split-KV flash attention, LDS-shared K/V, 8 waves/block -------------
// R15-proven structure (8 waves, grid 640, depth-1 counted-vmcnt, conflict-free V
// placement) with ONE change: XCD-aware block swizzle (T1). Consecutive blockIdx
// round-robin across the 8 XCDs; remapping wid2 = (bid&7)*80 + (bid>>3) gives each
// XCD a contiguous span of 80 work-ids = 4 complete bh-groups (20 blocks each),
// making each (b,h)'s K/V (~1MB) L2-resident within one XCD. Work mix per XCD is
// identical; long jobs still dispatched first within each group.
__global__ __launch_bounds__(512) void attn_chunk(const __hip_bfloat16* __restrict__ Qb,
                                                  const __hip_bfloat16* __restrict__ Kb,
                                                  const __hip_bfloat16* __restrict__ Vt,
                                                  __hip_bfloat16* __restrict__ Opart,
                                                  float* __restrict__ sbuf) {
  __shared__ __hip_bfloat16 Ks[2][2048];   // [32 kv][8 slots of 8 bf16], swizzled
  __shared__ __hip_bfloat16 Vs[2][2048];   // 256 granules, bank-spread placement
  int tid = threadIdx.x;
  int wid = tid >> 6, lane = tid & 63;
  int ql = lane & 31, hi = lane >> 5;

  int bid = blockIdx.x;
  // T1 swizzle: bijective over [0,640) = 8 XCDs x 80 work-ids
  int wid2 = (bid & 7) * 80 + (bid >> 3);
  int bh = wid2 / 20;
  int i  = wid2 % 20;
  int c, jbase, lenmax; bool diag;
  if (i < 12) {                          // full chunks (len 16)
    int pr = i;
    if (pr < 6)       { c = 0; jbase = 16 + 8*pr; }
    else if (pr < 10) { c = 1; jbase = 32 + 8*(pr-6); }
    else              { c = 2; jbase = 48 + 8*(pr-10); }
    lenmax = 16; diag = false;
  } else {                               // diagonal chunks; longer halves first (LPT)
    int e = i - 12;
    int hh = (e < 4) ? 1 : 0;
    c = e & 3;
    jbase = 16*c + 8*hh; lenmax = 8*hh + 8; diag = true;
  }
  int j = jbase + wid;
  int len = diag ? ((j & 15) + 1) : 16;
  int q0 = j * 32, t0 = c * 512;
  int jobid;
  if (!diag) jobid = (c == 0) ? (j - 16) : ((c == 1) ? (j + 16) : (j + 32));
  else       jobid = 96 + ((15 - (j & 15)) << 2) + c;
  int job = jobid * 32 + bh;

  const __hip_bfloat16* Qp = Qb + (size_t)bh * 2048 * 64;
  const __hip_bfloat16* Kp = Kb + (size_t)bh * 2048 * 64;
  const __hip_bfloat16* Vp = Vt + (size_t)bh * 64 * 2048;

  bf16x8 qf[4];
  #pragma unroll
  for (int cc = 0; cc < 4; ++cc)
    qf[cc] = *(const bf16x8*)&Qp[(size_t)(q0 + ql) * 64 + cc*16 + hi*8];

  f32x16 o0, o1;
  #pragma unroll
  for (int r = 0; r < 16; ++r) { o0[r] = 0.f; o1[r] = 0.f; }
  float s = 0.f;

  // staging thread roles (constant across iters)
  int kr = tid >> 3, ksl = tid & 7;                    // threads 0..255: K row/slot
  int vjj = tid - 256;                                 // threads 256..511: V granule L
  int ve  = (vjj >> 4) & 1;
  int vx  = vjj ^ (ve << 2);
  int vr  = vx >> 2;                                   // V source row d
  int vtc = (vx & 3) ^ (vr & 3);                       // V source 16B granule

#define ASTAGE(buf, it_)                                                                \
  do {                                                                                  \
    int kv0_ = t0 + (it_) * 32;                                                         \
    if (tid < 256)                                                                      \
      __builtin_amdgcn_global_load_lds(                                                 \
        (const __attribute__((address_space(1))) unsigned int*)                         \
          &Kp[(size_t)(kv0_ + kr) * 64 + ((ksl ^ (kr & 7)) * 8)],                       \
        (__attribute__((address_space(3))) unsigned int*)&Ks[buf][tid * 8], 16, 0, 0);  \
    else                                                                                \
      __builtin_amdgcn_global_load_lds(                                                 \
        (const __attribute__((address_space(1))) unsigned int*)                         \
          &Vp[(size_t)vr * 2048 + kv0_ + vtc * 8],                                      \
        (__attribute__((address_space(3))) unsigned int*)&Vs[buf][vjj * 8], 16, 0, 0);  \
  } while (0)

  ASTAGE(0, 0);
  for (int it = 0; it < lenmax; ++it) {
    int cur = it & 1;
    if (it + 1 < lenmax) {
      ASTAGE(cur ^ 1, it + 1);
      asm volatile("s_waitcnt vmcnt(1)" ::: "memory");   // tile it landed (own wave)
    } else {
      asm volatile("s_waitcnt vmcnt(0)" ::: "memory");
    }
    __builtin_amdgcn_s_barrier();                        // all waves' tile it landed
    __builtin_amdgcn_sched_barrier(0);

    if (it < len) {
      int kv0 = t0 + it * 32;
      bf16x8 kf[4], vf[4];
      #pragma unroll
      for (int cc = 0; cc < 4; ++cc)
        kf[cc] = *(const bf16x8*)&Ks[cur][ql * 64 + (((cc*2 + hi) ^ (ql & 7)) * 8)];
      #pragma unroll
      for (int g = 0; g < 2; ++g)
        #pragma unroll
        for (int cc = 0; cc < 2; ++cc) {
          int d_ = g*32 + ql, tc_ = cc*2 + hi;
          int L = (d_*4 + (tc_ ^ (d_ & 3))) ^ (((d_ >> 2) & 1) << 2);
          vf[g*2 + cc] = *(const bf16x8*)&Vs[cur][L * 8];
        }

      f32x16 st;
      #pragma unroll
      for (int r = 0; r < 16; ++r) st[r] = 0.f;
      #pragma unroll
      for (int cc = 0; cc < 4; ++cc) st = MFMA32(kf[cc], qf[cc], st);
      // st is in log2 units (Q pre-scaled by 0.125*log2e)

      if (diag && it == len - 1) {       // diagonal tile: causal mask
        #pragma unroll
        for (int r = 0; r < 16; ++r) {
          int kv = kv0 + (r & 3) + 8*(r >> 2) + 4*hi;
          if (kv > q0 + ql) st[r] = -1e30f;
        }
      }

      float p[16]; float ps = 0.f;
      #pragma unroll
      for (int r = 0; r < 16; ++r) { p[r] = exp2f(st[r]); ps += p[r]; }
      ps += __shfl_xor(ps, 32);
      s += ps;

      // P^T B-frag pack: pack own pairs to bf16 dwords, exchange cross-half dwords
      bf16x8 pb[2];
      #pragma unroll
      for (int cc = 0; cc < 2; ++cc) {
        unsigned w0 = pk2(p[cc*8+0], p[cc*8+1]);
        unsigned w1 = pk2(p[cc*8+2], p[cc*8+3]);
        unsigned w2 = pk2(p[cc*8+4], p[cc*8+5]);
        unsigned w3 = pk2(p[cc*8+6], p[cc*8+7]);
        unsigned r0 = __shfl_xor(hi ? w0 : w2, 32);
        unsigned r1 = __shfl_xor(hi ? w1 : w3, 32);
        u32x4 pw;
        pw[0] = hi ? r0 : w0;
        pw[1] = hi ? r1 : w1;
        pw[2] = hi ? w2 : r0;
        pw[3] = hi ? w3 : r1;
        pb[cc] = __builtin_bit_cast(bf16x8, pw);
      }

      o0 = MFMA32(vf[0], pb[0], o0);
      o0 = MFMA32(vf[1], pb[1], o0);
      o1 = MFMA32(vf[2], pb[0], o1);
      o1 = MFMA32(vf[3], pb[1], o1);
    }
    __builtin_amdgcn_s_barrier();                        // readers done before overwrite
  }
#undef ASTAGE

  // write UNNORMALIZED partial: Opart[job][ql][d] (bf16, [32][64] per job), sbuf[job][ql]=s
  __hip_bfloat16* Op = Opart + (size_t)job * 2048 + ql * 64;
  #pragma unroll
  for (int rr = 0; rr < 4; ++rr) {
    bf16x4 w;
    #pragma unroll
    for (int e = 0; e < 4; ++e) w[e] = (__bf16)o0[rr*4 + e];
    *(bf16x4*)&Op[8*rr + 4*hi] = w;
  }
  #pragma unroll
  for (int rr = 0; rr < 4; ++rr) {
    bf16x4 w;
    #pragma unroll
    for (int e = 0; e < 4; ++e) w[e] = (__bf16)o1[rr*4 + e];
    *(bf16x4*)&Op[32 + 8*rr + 4*hi] = w;
  }
  if (hi == 0) sbuf[(size_t)job * 32 + ql] = s;
}

// ------------- combine partials: per (b,h,j) sum <=4 chunks, normalize, write Ob -------------
__global__ __launch_bounds__(64) void attn_combine(const __hip_bfloat16* __restrict__ Opart,
                                                   const float* __restrict__ sbuf,
                                                   __hip_bfloat16* __restrict__ Ob) {
  int bid2 = blockIdx.x;              // 2048 = 64 j x 32 bh
  int j = bid2 >> 5, bh = bid2 & 31;
  int h = bh & 15, b = bh >> 4;
  int tid = threadIdx.x, ql = tid & 31, half = tid >> 5;
  int nc = (j >> 4) + 1;

  int gs[4];
  const int Sseg[3] = {0, 48, 80};
  #pragma unroll
  for (int i = 0; i < 3; ++i)
    if (i < nc - 1) gs[i] = (Sseg[i] + j - 16*(i+1)) * 32 + bh;
  gs[nc-1] = (96 + 4*(15 - (j & 15)) + (j >> 4)) * 32 + bh;

  float Ssum = 0.f;
  #pragma unroll
  for (int i = 0; i < 4; ++i)
    if (i < nc) Ssum += sbuf[(size_t)gs[i]*32 + ql];

  float acc[32];
  #pragma unroll
  for (int e = 0; e < 32; ++e) acc[e] = 0.f;
  #pragma unroll
  for (int i = 0; i < 4; ++i)
    if (i < nc) {
      const bf16x8* src = (const bf16x8*)(Opart + (size_t)gs[i]*2048 + ql*64 + half*32);
      #pragma unroll
      for (int q4 = 0; q4 < 4; ++q4) {
        bf16x8 v = src[q4];
        #pragma unroll
        for (int e = 0; e < 8; ++e) acc[q4*8 + e] += (float)v[e];
      }
    }

  float inv = 1.f / Ssum;
  size_t row = (size_t)b * 2048 + j*32 + ql;
  __hip_bfloat16* dst = Ob + row * 1024 + h*64 + half*32;
  #pragma unroll
  for (int q4 = 0; q4 < 4; ++q4) {
    bf16x8 w;
    #pragma unroll
    for (int e = 0; e < 8; ++e) w[e] = (__bf16)(acc[q4*8 + e] * inv);
    *(bf16x8*)&dst[q4*8] = w;
  }
}

// ---------------------------------------------------------------------------
extern "C" void kernel_launch(void* const* d_in, const int* in_sizes, int n_in,
                              void* d_out, int out_size, void* d_ws, size_t ws_size,
                              hipStream_t stream) {
  const float* x     = (const float*)d_in[0];
  // d_in[1] = mask (fixed causal triu) — implemented analytically
  const float* Wqkv  = (const float*)d_in[2];
  const float* Wproj = (const float*)d_in[3];
  float* out = (float*)d_out;

  char* ws = (char*)d_ws;
  const size_t MB = 1024 * 1024;
  __hip_bfloat16* xb  = (__hip_bfloat16*)(ws);            //  8 MB  [4096][1024]
  __hip_bfloat16* Wqt = (__hip_bfloat16*)(ws +  8*MB);    //  6 MB  [3072][1024]
  __hip_bfloat16* Wpt = (__hip_bfloat16*)(ws + 14*MB);    //  2 MB  [1024][1024]
  __hip_bfloat16* qkv = (__hip_bfloat16*)(ws + 16*MB);    // 24 MB  [4096][3072]
  __hip_bfloat16* Qb  = (__hip_bfloat16*)(ws + 40*MB);    //  8 MB  [B,H,T,64]
  __hip_bfloat16* Kb  = (__hip_bfloat16*)(ws + 48*MB);    //  8 MB
  __hip_bfloat16* Vt  = (__hip_bfloat16*)(ws + 56*MB);    //  8 MB  [B,H,64,T]
  __hip_bfloat16* Ob  = (__hip_bfloat16*)(ws + 64*MB);    //  8 MB  [4096][1024]
  // attn partials overlay the dead qkv region (qkv unused after rope/v_transpose)
  __hip_bfloat16* Opart = (__hip_bfloat16*)(ws + 16*MB);  // 20 MB  [5120][32][64]
  float*          sbuf  = (float*)(ws + 36*MB);           // 640KB  [5120][32]
  // sin/cos table overlays the dead Wqt region (Wqt unused after first gemm)
  float2*         sctbl = (float2*)(ws + 8*MB);           // 512KB  [2048*32]

  cast_f32_bf16<<<4096, 256, 0, stream>>>(x, xb, 1048576);
  transpose_cast<<<dim3(96, 32), 256, 0, stream>>>(Wqkv, Wqt, 1024, 3072);
  transpose_cast<<<dim3(32, 32), 256, 0, stream>>>(Wproj, Wpt, 1024, 1024);
  gemm_bt<__hip_bfloat16><<<dim3(24, 32), 256, 0, stream>>>(xb, Wqt, qkv, 4096, 3072, 1024);
  build_sincos<<<256, 256, 0, stream>>>(sctbl);
  rope_qk<<<1024, 256, 0, stream>>>(qkv, sctbl, Qb, Kb);
  v_transpose<<<1024, 256, 0, stream>>>(qkv, Vt);
  attn_chunk<<<640, 512, 0, stream>>>(Qb, Kb, Vt, Opart, sbuf);
  attn_combine<<<2048, 64, 0, stream>>>(Opart, sbuf, Ob);
  gemm_bt<float><<<dim3(8, 32), 256, 0, stream>>>(Ob, Wpt, out, 4096, 1024, 1024);
}

// Round 22
// 123.876 us; speedup vs baseline: 1.1535x; 1.1114x over previous
//
#include <hip/hip_runtime.h>
#include <hip/hip_bf16.h>

typedef __bf16  bf16x8 __attribute__((ext_vector_type(8)));
typedef __bf16  bf16x4 __attribute__((ext_vector_type(4)));
typedef __bf16  bf16x2 __attribute__((ext_vector_type(2)));
typedef float   f32x4  __attribute__((ext_vector_type(4)));
typedef float   f32x16 __attribute__((ext_vector_type(16)));
typedef unsigned u32x4 __attribute__((ext_vector_type(4)));

#define MFMA16(a,b,c) __builtin_amdgcn_mfma_f32_16x16x32_bf16(a,b,c,0,0,0)
#define MFMA32(a,b,c) __builtin_amdgcn_mfma_f32_32x32x16_bf16(a,b,c,0,0,0)

// B=2, T=2048, D=1024, H=16, Dh=64

// ---------------- cast x (fp32 -> bf16), 4 elems/thread ----------------
struct bf4 { __hip_bfloat16 a,b,c,d; };

__global__ __launch_bounds__(256) void cast_f32_bf16(const float* __restrict__ in,
                                                     __hip_bfloat16* __restrict__ out,
                                                     int n4) {
  int i = blockIdx.x * 256 + threadIdx.x;
  if (i >= n4) return;
  float4 v = ((const float4*)in)[i];
  bf4 o { __float2bfloat16(v.x), __float2bfloat16(v.y),
          __float2bfloat16(v.z), __float2bfloat16(v.w) };
  ((bf4*)out)[i] = o;
}

// ------------- transpose + cast: W[R][C] fp32 -> WT[C][R] bf16 -------------
__global__ __launch_bounds__(256) void transpose_cast(const float* __restrict__ W,
                                                      __hip_bfloat16* __restrict__ WT,
                                                      int R, int C) {
  __shared__ float tile[32][33];
  int c0 = blockIdx.x * 32, r0 = blockIdx.y * 32;
  int tx = threadIdx.x & 31, ty = threadIdx.x >> 5;   // 32 x 8
  #pragma unroll
  for (int i = 0; i < 32; i += 8)
    tile[ty + i][tx] = W[(size_t)(r0 + ty + i) * C + c0 + tx];
  __syncthreads();
  #pragma unroll
  for (int i = 0; i < 32; i += 8)
    WT[(size_t)(c0 + ty + i) * R + r0 + tx] = __float2bfloat16(tile[tx][ty + i]);
}

// ------------- sin/cos table: tbl[t*32+i] = {sin,cos}(t * 10000^(-i/32)) -------------
__global__ __launch_bounds__(256) void build_sincos(float2* __restrict__ tbl) {
  int idx = blockIdx.x * 256 + threadIdx.x;   // 65536 = 2048 t x 32 i
  int i = idx & 31, t = idx >> 5;
  float theta = expf(-9.210340371976184f * (float)i * 0.03125f);  // 10000^(-i/32)
  float sn, cs;
  sincosf((float)t * theta, &sn, &cs);
  tbl[idx] = float2{sn, cs};
}

// ------------- fused QKV GEMM: qkv = xb @ WqtT, epilogue does RoPE + reorg -------------
// Main loop = R10/R15-proven 128x128 BK=32 double-buffered counted-vmcnt pipeline.
// Epilogue by column region (uniform per block, since 1024 % 128 == 0):
//   region 0 (Q): RoPE rotate in-register (partners acc[mf][nf] / acc[mf][nf+2]),
//                 scale by QS, write Qb[b,h][t][64]
//   region 1 (K): RoPE rotate, write Kb
//   region 2 (V): transpose 128t x 128d through LDS (reusing staging smem), write Vt
__global__ __launch_bounds__(256) void gemm_qkv(const __hip_bfloat16* __restrict__ A,
                                                const __hip_bfloat16* __restrict__ BT,
                                                const float2* __restrict__ tbl,
                                                __hip_bfloat16* __restrict__ Qb,
                                                __hip_bfloat16* __restrict__ Kb,
                                                __hip_bfloat16* __restrict__ Vt) {
  __shared__ __align__(16) char smem[34816];   // max(As+Bs = 32KB, Vl = 128*136*2)
  auto As = (__hip_bfloat16 (*)[128][32])(smem);
  auto Bs = (__hip_bfloat16 (*)[128][32])(smem + 16384);
  auto Vl = (__hip_bfloat16 (*)[136])(smem);
  const int K = 1024;
  int tid  = threadIdx.x;
  int lane = tid & 63, wid = tid >> 6;
  int wm = wid >> 1, wn = wid & 1;
  int rowBase = blockIdx.y * 128;
  int colBase = blockIdx.x * 128;
  int lr = lane & 15, lg = lane >> 4;

  f32x4 acc[4][4];
  #pragma unroll
  for (int i = 0; i < 4; ++i)
    #pragma unroll
    for (int j = 0; j < 4; ++j) acc[i][j] = f32x4{0.f,0.f,0.f,0.f};

  int nt = K >> 5;

#define GSTAGE(buf, kt)                                                                 \
  do {                                                                                  \
    int k0_ = (kt) << 5;                                                                \
    _Pragma("unroll")                                                                   \
    for (int p = 0; p < 2; ++p) {                                                       \
      int idx = p * 256 + tid;                                                          \
      int r_ = idx >> 2, sl_ = idx & 3;                                                 \
      __builtin_amdgcn_global_load_lds(                                                 \
        (const __attribute__((address_space(1))) unsigned int*)                         \
          &A[(size_t)(rowBase + r_) * K + k0_ + ((sl_ ^ (r_ & 3)) * 8)],                \
        (__attribute__((address_space(3))) unsigned int*)&As[buf][r_][sl_ * 8], 16, 0, 0);\
      __builtin_amdgcn_global_load_lds(                                                 \
        (const __attribute__((address_space(1))) unsigned int*)                         \
          &BT[(size_t)(colBase + r_) * K + k0_ + ((sl_ ^ (r_ & 3)) * 8)],               \
        (__attribute__((address_space(3))) unsigned int*)&Bs[buf][r_][sl_ * 8], 16, 0, 0);\
    }                                                                                   \
  } while (0)

  GSTAGE(0, 0);
  for (int t = 0; t < nt; ++t) {
    int cur = t & 1;
    if (t + 1 < nt) {
      GSTAGE(cur ^ 1, t + 1);
      asm volatile("s_waitcnt vmcnt(4)" ::: "memory");   // tile t landed (own wave)
    } else {
      asm volatile("s_waitcnt vmcnt(0)" ::: "memory");
    }
    __builtin_amdgcn_s_barrier();                        // all waves' tile t landed
    __builtin_amdgcn_sched_barrier(0);

    bf16x8 af[4], bfr[4];
    #pragma unroll
    for (int mf = 0; mf < 4; ++mf) {
      int row = wm*64 + mf*16 + lr;
      af[mf]  = *(const bf16x8*)&As[cur][row][((lg ^ (lr & 3)) * 8)];
    }
    #pragma unroll
    for (int nf = 0; nf < 4; ++nf) {
      int row = wn*64 + nf*16 + lr;
      bfr[nf] = *(const bf16x8*)&Bs[cur][row][((lg ^ (lr & 3)) * 8)];
    }
    #pragma unroll
    for (int mf = 0; mf < 4; ++mf)
      #pragma unroll
      for (int nf = 0; nf < 4; ++nf)
        acc[mf][nf] = MFMA16(af[mf], bfr[nf], acc[mf][nf]);

    __builtin_amdgcn_s_barrier();                        // readers done before overwrite
  }
#undef GSTAGE

  int region = colBase >> 10;                  // 0=Q, 1=K, 2=V
  int b = rowBase >> 11;
  if (region < 2) {
    const float QS = 0.18033688011112042f;     // (1/8) * log2(e)
    __hip_bfloat16* dst = (region == 0) ? Qb : Kb;
    float scale = (region == 0) ? QS : 1.0f;
    int h = ((colBase & 1023) >> 6) + wn;
    #pragma unroll
    for (int mf = 0; mf < 4; ++mf)
      #pragma unroll
      for (int r = 0; r < 4; ++r) {
        int row = rowBase + wm*64 + mf*16 + lg*4 + r;
        int t = row & 2047;
        #pragma unroll
        for (int nf = 0; nf < 2; ++nf) {
          int i = nf*16 + lr;                  // 0..31
          float2 sc = tbl[(t << 5) + i];
          float v1 = acc[mf][nf][r], v2 = acc[mf][nf+2][r];
          size_t base = ((size_t)((b*16 + h) * 2048 + t)) * 64;
          dst[base + i]      = __float2bfloat16(( v1*sc.y + v2*sc.x) * scale);
          dst[base + 32 + i] = __float2bfloat16((-v1*sc.x + v2*sc.y) * scale);
        }
      }
  } else {
    // V: stage acc into LDS d-major, then coalesced-ish copy-out transposed
    #pragma unroll
    for (int nf = 0; nf < 4; ++nf) {
      int d = wn*64 + nf*16 + lr;
      #pragma unroll
      for (int mf = 0; mf < 4; ++mf) {
        bf16x4 w;
        #pragma unroll
        for (int r = 0; r < 4; ++r) w[r] = (__bf16)acc[mf][nf][r];
        *(bf16x4*)&Vl[d][wm*64 + mf*16 + lg*4] = w;
      }
    }
    __syncthreads();
    int vd = tid >> 1, half = tid & 1;
    int h = ((colBase - 2048) >> 6) + (vd >> 6);
    int dloc = vd & 63;
    __hip_bfloat16* dstp = Vt + ((size_t)(b*16 + h) * 64 + dloc) * 2048
                              + (rowBase & 2047) + half*64;
    const __hip_bfloat16* srcp = &Vl[vd][half*64];
    #pragma unroll
    for (int g = 0; g < 8; ++g)
      *(bf16x8*)&dstp[g*8] = *(const bf16x8*)&srcp[g*8];
  }
}

// ------------- GEMM: C[M][N] = A[M][K] * BT[N][K]^T  (bf16 in, OutT out) -------------
// 128x128 tile, BK=32, double-buffered LDS with COUNTED vmcnt pipeline (proven R10/R15)
template <typename OutT>
__global__ __launch_bounds__(256) void gemm_bt(const __hip_bfloat16* __restrict__ A,
                                               const __hip_bfloat16* __restrict__ BT,
                                               OutT* __restrict__ C,
                                               int M, int N, int K) {
  __shared__ __hip_bfloat16 As[2][128][32];
  __shared__ __hip_bfloat16 Bs[2][128][32];
  int tid  = threadIdx.x;
  int lane = tid & 63, wid = tid >> 6;
  int wm = wid >> 1, wn = wid & 1;
  int rowBase = blockIdx.y * 128;
  int colBase = blockIdx.x * 128;
  int lr = lane & 15, lg = lane >> 4;

  f32x4 acc[4][4];
  #pragma unroll
  for (int i = 0; i < 4; ++i)
    #pragma unroll
    for (int j = 0; j < 4; ++j) acc[i][j] = f32x4{0.f,0.f,0.f,0.f};

  int nt = K >> 5;

#define GSTAGE(buf, kt)                                                                 \
  do {                                                                                  \
    int k0_ = (kt) << 5;                                                                \
    _Pragma("unroll")                                                                   \
    for (int p = 0; p < 2; ++p) {                                                       \
      int idx = p * 256 + tid;                                                          \
      int r_ = idx >> 2, sl_ = idx & 3;                                                 \
      __builtin_amdgcn_global_load_lds(                                                 \
        (const __attribute__((address_space(1))) unsigned int*)                         \
          &A[(size_t)(rowBase + r_) * K + k0_ + ((sl_ ^ (r_ & 3)) * 8)],                \
        (__attribute__((address_space(3))) unsigned int*)&As[buf][r_][sl_ * 8], 16, 0, 0);\
      __builtin_amdgcn_global_load_lds(                                                 \
        (const __attribute__((address_space(1))) unsigned int*)                         \
          &BT[(size_t)(colBase + r_) * K + k0_ + ((sl_ ^ (r_ & 3)) * 8)],               \
        (__attribute__((address_space(3))) unsigned int*)&Bs[buf][r_][sl_ * 8], 16, 0, 0);\
    }                                                                                   \
  } while (0)

  GSTAGE(0, 0);
  for (int t = 0; t < nt; ++t) {
    int cur = t & 1;
    if (t + 1 < nt) {
      GSTAGE(cur ^ 1, t + 1);
      asm volatile("s_waitcnt vmcnt(4)" ::: "memory");   // tile t landed (own wave)
    } else {
      asm volatile("s_waitcnt vmcnt(0)" ::: "memory");
    }
    __builtin_amdgcn_s_barrier();                        // all waves' tile t landed
    __builtin_amdgcn_sched_barrier(0);

    bf16x8 af[4], bfr[4];
    #pragma unroll
    for (int mf = 0; mf < 4; ++mf) {
      int row = wm*64 + mf*16 + lr;
      af[mf]  = *(const bf16x8*)&As[cur][row][((lg ^ (lr & 3)) * 8)];
    }
    #pragma unroll
    for (int nf = 0; nf < 4; ++nf) {
      int row = wn*64 + nf*16 + lr;
      bfr[nf] = *(const bf16x8*)&Bs[cur][row][((lg ^ (lr & 3)) * 8)];
    }
    #pragma unroll
    for (int mf = 0; mf < 4; ++mf)
      #pragma unroll
      for (int nf = 0; nf < 4; ++nf)
        acc[mf][nf] = MFMA16(af[mf], bfr[nf], acc[mf][nf]);

    __builtin_amdgcn_s_barrier();                        // readers done before overwrite
  }
#undef GSTAGE

  #pragma unroll
  for (int mf = 0; mf < 4; ++mf)
    #pragma unroll
    for (int nf = 0; nf < 4; ++nf)
      #pragma unroll
      for (int r = 0; r < 4; ++r) {
        int row = rowBase + wm*64 + mf*16 + lg*4 + r;
        int col = colBase + wn*64 + nf*16 + lr;
        float v = acc[mf][nf][r];
        if constexpr (sizeof(OutT) == 2) C[(size_t)row * N + col] = __float2bfloat16(v);
        else                             C[(size_t)row * N + col] = v;
      }
}

// pack two floats to one dword of 2 bf16 (compiler emits v_cvt_pk_bf16_f32)
__device__ __forceinline__ unsigned pk2(float lo, float hi_) {
  bf16x2 t; t[0] = (__bf16)lo; t[1] = (__bf16)hi_;
  return __builtin_bit_cast(unsigned, t);
}

// ------------- Split-KV flash attention, LDS-shared K/V, 8 waves/block -------------
// Exact R15-proven version (44.7us): 8 waves, grid 640, depth-1 counted-vmcnt
// double-buffer, conflict-free V placement. No XCD swizzle (R19: cut FETCH 3.4x
// but cost +6us -> not bandwidth-bound).
__global__ __launch_bounds__(512) void attn_chunk(const __hip_bfloat16* __restrict__ Qb,
                                                  const __hip_bfloat16* __restrict__ Kb,
                                                  const __hip_bfloat16* __restrict__ Vt,
                                                  __hip_bfloat16* __restrict__ Opart,
                                                  float* __restrict__ sbuf) {
  __shared__ __hip_bfloat16 Ks[2][2048];   // [32 kv][8 slots of 8 bf16], swizzled
  __shared__ __hip_bfloat16 Vs[2][2048];   // 256 granules, bank-spread placement
  int tid = threadIdx.x;
  int wid = tid >> 6, lane = tid & 63;
  int ql = lane & 31, hi = lane >> 5;

  int bid = blockIdx.x;
  int bh, c, jbase, lenmax; bool diag;
  if (bid < 384) {                       // full chunks (len 16)
    bh = bid / 12; int pr = bid % 12;
    if (pr < 6)       { c = 0; jbase = 16 + 8*pr; }
    else if (pr < 10) { c = 1; jbase = 32 + 8*(pr-6); }
    else              { c = 2; jbase = 48 + 8*(pr-10); }
    lenmax = 16; diag = false;
  } else {                               // diagonal chunks; longer halves first (LPT)
    int e = bid - 384;
    int hh = (e < 128) ? 1 : 0;
    int e2 = e & 127;
    bh = e2 >> 2; c = e2 & 3;
    jbase = 16*c + 8*hh; lenmax = 8*hh + 8; diag = true;
  }
  int j = jbase + wid;
  int len = diag ? ((j & 15) + 1) : 16;
  int q0 = j * 32, t0 = c * 512;
  int jobid;
  if (!diag) jobid = (c == 0) ? (j - 16) : ((c == 1) ? (j + 16) : (j + 32));
  else       jobid = 96 + ((15 - (j & 15)) << 2) + c;
  int job = jobid * 32 + bh;

  const __hip_bfloat16* Qp = Qb + (size_t)bh * 2048 * 64;
  const __hip_bfloat16* Kp = Kb + (size_t)bh * 2048 * 64;
  const __hip_bfloat16* Vp = Vt + (size_t)bh * 64 * 2048;

  bf16x8 qf[4];
  #pragma unroll
  for (int cc = 0; cc < 4; ++cc)
    qf[cc] = *(const bf16x8*)&Qp[(size_t)(q0 + ql) * 64 + cc*16 + hi*8];

  f32x16 o0, o1;
  #pragma unroll
  for (int r = 0; r < 16; ++r) { o0[r] = 0.f; o1[r] = 0.f; }
  float s = 0.f;

  // staging thread roles (constant across iters)
  int kr = tid >> 3, ksl = tid & 7;                    // threads 0..255: K row/slot
  int vjj = tid - 256;                                 // threads 256..511: V granule L
  int ve  = (vjj >> 4) & 1;
  int vx  = vjj ^ (ve << 2);
  int vr  = vx >> 2;                                   // V source row d
  int vtc = (vx & 3) ^ (vr & 3);                       // V source 16B granule

#define ASTAGE(buf, it_)                                                                \
  do {                                                                                  \
    int kv0_ = t0 + (it_) * 32;                                                         \
    if (tid < 256)                                                                      \
      __builtin_amdgcn_global_load_lds(                                                 \
        (const __attribute__((address_space(1))) unsigned int*)                         \
          &Kp[(size_t)(kv0_ + kr) * 64 + ((ksl ^ (kr & 7)) * 8)],                       \
        (__attribute__((address_space(3))) unsigned int*)&Ks[buf][tid * 8], 16, 0, 0);  \
    else                                                                                \
      __builtin_amdgcn_global_load_lds(                                                 \
        (const __attribute__((address_space(1))) unsigned int*)                         \
          &Vp[(size_t)vr * 2048 + kv0_ + vtc * 8],                                      \
        (__attribute__((address_space(3))) unsigned int*)&Vs[buf][vjj * 8], 16, 0, 0);  \
  } while (0)

  ASTAGE(0, 0);
  for (int it = 0; it < lenmax; ++it) {
    int cur = it & 1;
    if (it + 1 < lenmax) {
      ASTAGE(cur ^ 1, it + 1);
      asm volatile("s_waitcnt vmcnt(1)" ::: "memory");   // tile it landed (own wave)
    } else {
      asm volatile("s_waitcnt vmcnt(0)" ::: "memory");
    }
    __builtin_amdgcn_s_barrier();                        // all waves' tile it landed
    __builtin_amdgcn_sched_barrier(0);

    if (it < len) {
      int kv0 = t0 + it * 32;
      bf16x8 kf[4], vf[4];
      #pragma unroll
      for (int cc = 0; cc < 4; ++cc)
        kf[cc] = *(const bf16x8*)&Ks[cur][ql * 64 + (((cc*2 + hi) ^ (ql & 7)) * 8)];
      #pragma unroll
      for (int g = 0; g < 2; ++g)
        #pragma unroll
        for (int cc = 0; cc < 2; ++cc) {
          int d_ = g*32 + ql, tc_ = cc*2 + hi;
          int L = (d_*4 + (tc_ ^ (d_ & 3))) ^ (((d_ >> 2) & 1) << 2);
          vf[g*2 + cc] = *(const bf16x8*)&Vs[cur][L * 8];
        }

      f32x16 st;
      #pragma unroll
      for (int r = 0; r < 16; ++r) st[r] = 0.f;
      #pragma unroll
      for (int cc = 0; cc < 4; ++cc) st = MFMA32(kf[cc], qf[cc], st);
      // st is in log2 units (Q pre-scaled by 0.125*log2e)

      if (diag && it == len - 1) {       // diagonal tile: causal mask
        #pragma unroll
        for (int r = 0; r < 16; ++r) {
          int kv = kv0 + (r & 3) + 8*(r >> 2) + 4*hi;
          if (kv > q0 + ql) st[r] = -1e30f;
        }
      }

      float p[16]; float ps = 0.f;
      #pragma unroll
      for (int r = 0; r < 16; ++r) { p[r] = exp2f(st[r]); ps += p[r]; }
      ps += __shfl_xor(ps, 32);
      s += ps;

      // P^T B-frag pack: pack own pairs to bf16 dwords, exchange cross-half dwords
      bf16x8 pb[2];
      #pragma unroll
      for (int cc = 0; cc < 2; ++cc) {
        unsigned w0 = pk2(p[cc*8+0], p[cc*8+1]);
        unsigned w1 = pk2(p[cc*8+2], p[cc*8+3]);
        unsigned w2 = pk2(p[cc*8+4], p[cc*8+5]);
        unsigned w3 = pk2(p[cc*8+6], p[cc*8+7]);
        unsigned r0 = __shfl_xor(hi ? w0 : w2, 32);
        unsigned r1 = __shfl_xor(hi ? w1 : w3, 32);
        u32x4 pw;
        pw[0] = hi ? r0 : w0;
        pw[1] = hi ? r1 : w1;
        pw[2] = hi ? w2 : r0;
        pw[3] = hi ? w3 : r1;
        pb[cc] = __builtin_bit_cast(bf16x8, pw);
      }

      o0 = MFMA32(vf[0], pb[0], o0);
      o0 = MFMA32(vf[1], pb[1], o0);
      o1 = MFMA32(vf[2], pb[0], o1);
      o1 = MFMA32(vf[3], pb[1], o1);
    }
    __builtin_amdgcn_s_barrier();                        // readers done before overwrite
  }
#undef ASTAGE

  // write UNNORMALIZED partial: Opart[job][ql][d] (bf16, [32][64] per job), sbuf[job][ql]=s
  __hip_bfloat16* Op = Opart + (size_t)job * 2048 + ql * 64;
  #pragma unroll
  for (int rr = 0; rr < 4; ++rr) {
    bf16x4 w;
    #pragma unroll
    for (int e = 0; e < 4; ++e) w[e] = (__bf16)o0[rr*4 + e];
    *(bf16x4*)&Op[8*rr + 4*hi] = w;
  }
  #pragma unroll
  for (int rr = 0; rr < 4; ++rr) {
    bf16x4 w;
    #pragma unroll
    for (int e = 0; e < 4; ++e) w[e] = (__bf16)o1[rr*4 + e];
    *(bf16x4*)&Op[32 + 8*rr + 4*hi] = w;
  }
  if (hi == 0) sbuf[(size_t)job * 32 + ql] = s;
}

// ------------- combine partials: per (b,h,j) sum <=4 chunks, normalize, write Ob -------------
__global__ __launch_bounds__(64) void attn_combine(const __hip_bfloat16* __restrict__ Opart,
                                                   const float* __restrict__ sbuf,
                                                   __hip_bfloat16* __restrict__ Ob) {
  int bid2 = blockIdx.x;              // 2048 = 64 j x 32 bh
  int j = bid2 >> 5, bh = bid2 & 31;
  int h = bh & 15, b = bh >> 4;
  int tid = threadIdx.x, ql = tid & 31, half = tid >> 5;
  int nc = (j >> 4) + 1;

  int gs[4];
  const int Sseg[3] = {0, 48, 80};
  #pragma unroll
  for (int i = 0; i < 3; ++i)
    if (i < nc - 1) gs[i] = (Sseg[i] + j - 16*(i+1)) * 32 + bh;
  gs[nc-1] = (96 + 4*(15 - (j & 15)) + (j >> 4)) * 32 + bh;

  float Ssum = 0.f;
  #pragma unroll
  for (int i = 0; i < 4; ++i)
    if (i < nc) Ssum += sbuf[(size_t)gs[i]*32 + ql];

  float acc[32];
  #pragma unroll
  for (int e = 0; e < 32; ++e) acc[e] = 0.f;
  #pragma unroll
  for (int i = 0; i < 4; ++i)
    if (i < nc) {
      const bf16x8* src = (const bf16x8*)(Opart + (size_t)gs[i]*2048 + ql*64 + half*32);
      #pragma unroll
      for (int q4 = 0; q4 < 4; ++q4) {
        bf16x8 v = src[q4];
        #pragma unroll
        for (int e = 0; e < 8; ++e) acc[q4*8 + e] += (float)v[e];
      }
    }

  float inv = 1.f / Ssum;
  size_t row = (size_t)b * 2048 + j*32 + ql;
  __hip_bfloat16* dst = Ob + row * 1024 + h*64 + half*32;
  #pragma unroll
  for (int q4 = 0; q4 < 4; ++q4) {
    bf16x8 w;
    #pragma unroll
    for (int e = 0; e < 8; ++e) w[e] = (__bf16)(acc[q4*8 + e] * inv);
    *(bf16x8*)&dst[q4*8] = w;
  }
}

// ---------------------------------------------------------------------------
extern "C" void kernel_launch(void* const* d_in, const int* in_sizes, int n_in,
                              void* d_out, int out_size, void* d_ws, size_t ws_size,
                              hipStream_t stream) {
  const float* x     = (const float*)d_in[0];
  // d_in[1] = mask (fixed causal triu) — implemented analytically
  const float* Wqkv  = (const float*)d_in[2];
  const float* Wproj = (const float*)d_in[3];
  float* out = (float*)d_out;

  char* ws = (char*)d_ws;
  const size_t MB = 1024 * 1024;
  __hip_bfloat16* xb  = (__hip_bfloat16*)(ws);            //  8 MB  [4096][1024]
  __hip_bfloat16* Wqt = (__hip_bfloat16*)(ws +  8*MB);    //  6 MB  [3072][1024]
  __hip_bfloat16* Wpt = (__hip_bfloat16*)(ws + 14*MB);    //  2 MB  [1024][1024]
  __hip_bfloat16* Qb  = (__hip_bfloat16*)(ws + 40*MB);    //  8 MB  [B,H,T,64]
  __hip_bfloat16* Kb  = (__hip_bfloat16*)(ws + 48*MB);    //  8 MB
  __hip_bfloat16* Vt  = (__hip_bfloat16*)(ws + 56*MB);    //  8 MB  [B,H,64,T]
  __hip_bfloat16* Ob  = (__hip_bfloat16*)(ws + 64*MB);    //  8 MB  [4096][1024]
  __hip_bfloat16* Opart = (__hip_bfloat16*)(ws + 16*MB);  // 20 MB  [5120][32][64]
  float*          sbuf  = (float*)(ws + 36*MB);           // 640KB  [5120][32]
  float2*         sctbl = (float2*)(ws + 37*MB);          // 512KB  [2048*32]

  cast_f32_bf16<<<4096, 256, 0, stream>>>(x, xb, 1048576);
  transpose_cast<<<dim3(96, 32), 256, 0, stream>>>(Wqkv, Wqt, 1024, 3072);
  transpose_cast<<<dim3(32, 32), 256, 0, stream>>>(Wproj, Wpt, 1024, 1024);
  build_sincos<<<256, 256, 0, stream>>>(sctbl);
  gemm_qkv<<<dim3(24, 32), 256, 0, stream>>>(xb, Wqt, sctbl, Qb, Kb, Vt);
  attn_chunk<<<640, 512, 0, stream>>>(Qb, Kb, Vt, Opart, sbuf);
  attn_combine<<<2048, 64, 0, stream>>>(Opart, sbuf, Ob);
  gemm_bt<float><<<dim3(8, 32), 256, 0, stream>>>(Ob, Wpt, out, 4096, 1024, 1024);
}

// Round 23
// 120.657 us; speedup vs baseline: 1.1843x; 1.0267x over previous
//
#include <hip/hip_runtime.h>
#include <hip/hip_bf16.h>

typedef __bf16  bf16x8 __attribute__((ext_vector_type(8)));
typedef __bf16  bf16x4 __attribute__((ext_vector_type(4)));
typedef __bf16  bf16x2 __attribute__((ext_vector_type(2)));
typedef float   f32x4  __attribute__((ext_vector_type(4)));
typedef float   f32x16 __attribute__((ext_vector_type(16)));
typedef unsigned u32x4 __attribute__((ext_vector_type(4)));

#define MFMA16(a,b,c) __builtin_amdgcn_mfma_f32_16x16x32_bf16(a,b,c,0,0,0)
#define MFMA32(a,b,c) __builtin_amdgcn_mfma_f32_32x32x16_bf16(a,b,c,0,0,0)

// B=2, T=2048, D=1024, H=16, Dh=64

// ---------------- cast x (fp32 -> bf16), 4 elems/thread ----------------
struct bf4 { __hip_bfloat16 a,b,c,d; };

__global__ __launch_bounds__(256) void cast_f32_bf16(const float* __restrict__ in,
                                                     __hip_bfloat16* __restrict__ out,
                                                     int n4) {
  int i = blockIdx.x * 256 + threadIdx.x;
  if (i >= n4) return;
  float4 v = ((const float4*)in)[i];
  bf4 o { __float2bfloat16(v.x), __float2bfloat16(v.y),
          __float2bfloat16(v.z), __float2bfloat16(v.w) };
  ((bf4*)out)[i] = o;
}

// ------------- transpose + cast: W[R][C] fp32 -> WT[C][R] bf16 -------------
__global__ __launch_bounds__(256) void transpose_cast(const float* __restrict__ W,
                                                      __hip_bfloat16* __restrict__ WT,
                                                      int R, int C) {
  __shared__ float tile[32][33];
  int c0 = blockIdx.x * 32, r0 = blockIdx.y * 32;
  int tx = threadIdx.x & 31, ty = threadIdx.x >> 5;   // 32 x 8
  #pragma unroll
  for (int i = 0; i < 32; i += 8)
    tile[ty + i][tx] = W[(size_t)(r0 + ty + i) * C + c0 + tx];
  __syncthreads();
  #pragma unroll
  for (int i = 0; i < 32; i += 8)
    WT[(size_t)(c0 + ty + i) * R + r0 + tx] = __float2bfloat16(tile[tx][ty + i]);
}

// ------------- sin/cos table: tbl[t*32+i] = {sin,cos}(t * 10000^(-i/32)) -------------
__global__ __launch_bounds__(256) void build_sincos(float2* __restrict__ tbl) {
  int idx = blockIdx.x * 256 + threadIdx.x;   // 65536 = 2048 t x 32 i
  int i = idx & 31, t = idx >> 5;
  float theta = expf(-9.210340371976184f * (float)i * 0.03125f);  // 10000^(-i/32)
  float sn, cs;
  sincosf((float)t * theta, &sn, &cs);
  tbl[idx] = float2{sn, cs};
}

// ------------- fused QKV GEMM: qkv = xb @ WqtT, epilogue does RoPE + reorg -------------
// Main loop = R10/R15-proven 128x128 BK=32 double-buffered counted-vmcnt pipeline.
// Epilogue by column region (uniform per block, since 1024 % 128 == 0):
//   region 0 (Q): RoPE rotate in-register, scale by QS, write Qb
//   region 1 (K): RoPE rotate, write Kb
//   region 2 (V): transpose 128t x 128d through LDS, write Vt
__global__ __launch_bounds__(256) void gemm_qkv(const __hip_bfloat16* __restrict__ A,
                                                const __hip_bfloat16* __restrict__ BT,
                                                const float2* __restrict__ tbl,
                                                __hip_bfloat16* __restrict__ Qb,
                                                __hip_bfloat16* __restrict__ Kb,
                                                __hip_bfloat16* __restrict__ Vt) {
  __shared__ __align__(16) char smem[34816];   // max(As+Bs = 32KB, Vl = 128*136*2)
  auto As = (__hip_bfloat16 (*)[128][32])(smem);
  auto Bs = (__hip_bfloat16 (*)[128][32])(smem + 16384);
  auto Vl = (__hip_bfloat16 (*)[136])(smem);
  const int K = 1024;
  int tid  = threadIdx.x;
  int lane = tid & 63, wid = tid >> 6;
  int wm = wid >> 1, wn = wid & 1;
  int rowBase = blockIdx.y * 128;
  int colBase = blockIdx.x * 128;
  int lr = lane & 15, lg = lane >> 4;

  f32x4 acc[4][4];
  #pragma unroll
  for (int i = 0; i < 4; ++i)
    #pragma unroll
    for (int j = 0; j < 4; ++j) acc[i][j] = f32x4{0.f,0.f,0.f,0.f};

  int nt = K >> 5;

#define GSTAGE(buf, kt)                                                                 \
  do {                                                                                  \
    int k0_ = (kt) << 5;                                                                \
    _Pragma("unroll")                                                                   \
    for (int p = 0; p < 2; ++p) {                                                       \
      int idx = p * 256 + tid;                                                          \
      int r_ = idx >> 2, sl_ = idx & 3;                                                 \
      __builtin_amdgcn_global_load_lds(                                                 \
        (const __attribute__((address_space(1))) unsigned int*)                         \
          &A[(size_t)(rowBase + r_) * K + k0_ + ((sl_ ^ (r_ & 3)) * 8)],                \
        (__attribute__((address_space(3))) unsigned int*)&As[buf][r_][sl_ * 8], 16, 0, 0);\
      __builtin_amdgcn_global_load_lds(                                                 \
        (const __attribute__((address_space(1))) unsigned int*)                         \
          &BT[(size_t)(colBase + r_) * K + k0_ + ((sl_ ^ (r_ & 3)) * 8)],               \
        (__attribute__((address_space(3))) unsigned int*)&Bs[buf][r_][sl_ * 8], 16, 0, 0);\
    }                                                                                   \
  } while (0)

  GSTAGE(0, 0);
  for (int t = 0; t < nt; ++t) {
    int cur = t & 1;
    if (t + 1 < nt) {
      GSTAGE(cur ^ 1, t + 1);
      asm volatile("s_waitcnt vmcnt(4)" ::: "memory");   // tile t landed (own wave)
    } else {
      asm volatile("s_waitcnt vmcnt(0)" ::: "memory");
    }
    __builtin_amdgcn_s_barrier();                        // all waves' tile t landed
    __builtin_amdgcn_sched_barrier(0);

    bf16x8 af[4], bfr[4];
    #pragma unroll
    for (int mf = 0; mf < 4; ++mf) {
      int row = wm*64 + mf*16 + lr;
      af[mf]  = *(const bf16x8*)&As[cur][row][((lg ^ (lr & 3)) * 8)];
    }
    #pragma unroll
    for (int nf = 0; nf < 4; ++nf) {
      int row = wn*64 + nf*16 + lr;
      bfr[nf] = *(const bf16x8*)&Bs[cur][row][((lg ^ (lr & 3)) * 8)];
    }
    #pragma unroll
    for (int mf = 0; mf < 4; ++mf)
      #pragma unroll
      for (int nf = 0; nf < 4; ++nf)
        acc[mf][nf] = MFMA16(af[mf], bfr[nf], acc[mf][nf]);

    __builtin_amdgcn_s_barrier();                        // readers done before overwrite
  }
#undef GSTAGE

  int region = colBase >> 10;                  // 0=Q, 1=K, 2=V
  int b = rowBase >> 11;
  if (region < 2) {
    const float QS = 0.18033688011112042f;     // (1/8) * log2(e)
    __hip_bfloat16* dst = (region == 0) ? Qb : Kb;
    float scale = (region == 0) ? QS : 1.0f;
    int h = ((colBase & 1023) >> 6) + wn;
    #pragma unroll
    for (int mf = 0; mf < 4; ++mf)
      #pragma unroll
      for (int r = 0; r < 4; ++r) {
        int row = rowBase + wm*64 + mf*16 + lg*4 + r;
        int t = row & 2047;
        #pragma unroll
        for (int nf = 0; nf < 2; ++nf) {
          int i = nf*16 + lr;                  // 0..31
          float2 sc = tbl[(t << 5) + i];
          float v1 = acc[mf][nf][r], v2 = acc[mf][nf+2][r];
          size_t base = ((size_t)((b*16 + h) * 2048 + t)) * 64;
          dst[base + i]      = __float2bfloat16(( v1*sc.y + v2*sc.x) * scale);
          dst[base + 32 + i] = __float2bfloat16((-v1*sc.x + v2*sc.y) * scale);
        }
      }
  } else {
    // V: stage acc into LDS d-major, then coalesced-ish copy-out transposed
    #pragma unroll
    for (int nf = 0; nf < 4; ++nf) {
      int d = wn*64 + nf*16 + lr;
      #pragma unroll
      for (int mf = 0; mf < 4; ++mf) {
        bf16x4 w;
        #pragma unroll
        for (int r = 0; r < 4; ++r) w[r] = (__bf16)acc[mf][nf][r];
        *(bf16x4*)&Vl[d][wm*64 + mf*16 + lg*4] = w;
      }
    }
    __syncthreads();
    int vd = tid >> 1, half = tid & 1;
    int h = ((colBase - 2048) >> 6) + (vd >> 6);
    int dloc = vd & 63;
    __hip_bfloat16* dstp = Vt + ((size_t)(b*16 + h) * 64 + dloc) * 2048
                              + (rowBase & 2047) + half*64;
    const __hip_bfloat16* srcp = &Vl[vd][half*64];
    #pragma unroll
    for (int g = 0; g < 8; ++g)
      *(bf16x8*)&dstp[g*8] = *(const bf16x8*)&srcp[g*8];
  }
}

// ------------- proj GEMM: C[M][N] = A[M][K] * BT[N][K]^T, fp32 out -------------
// 128x64 tile (512 blocks = 2 blocks/CU for M=4096,N=1024), BK=32, double-buffered
// counted-vmcnt pipeline (proven R10/R15 template; 3 loads/thread -> vmcnt(3)).
// Waves 2x2, each owning 64x32 (acc[4][2]). XOR slot-swizzle both sides.
__global__ __launch_bounds__(256) void gemm_proj(const __hip_bfloat16* __restrict__ A,
                                                 const __hip_bfloat16* __restrict__ BT,
                                                 float* __restrict__ C,
                                                 int M, int N, int K) {
  __shared__ __hip_bfloat16 As[2][128][32];
  __shared__ __hip_bfloat16 Bs[2][64][32];
  int tid  = threadIdx.x;
  int lane = tid & 63, wid = tid >> 6;
  int wm = wid >> 1, wn = wid & 1;
  int rowBase = blockIdx.y * 128;
  int colBase = blockIdx.x * 64;
  int lr = lane & 15, lg = lane >> 4;

  f32x4 acc[4][2];
  #pragma unroll
  for (int i = 0; i < 4; ++i)
    #pragma unroll
    for (int j = 0; j < 2; ++j) acc[i][j] = f32x4{0.f,0.f,0.f,0.f};

  int nt = K >> 5;

#define PSTAGE(buf, kt)                                                                 \
  do {                                                                                  \
    int k0_ = (kt) << 5;                                                                \
    _Pragma("unroll")                                                                   \
    for (int p = 0; p < 2; ++p) {                                                       \
      int idx = p * 256 + tid;                                                          \
      int r_ = idx >> 2, sl_ = idx & 3;                                                 \
      __builtin_amdgcn_global_load_lds(                                                 \
        (const __attribute__((address_space(1))) unsigned int*)                         \
          &A[(size_t)(rowBase + r_) * K + k0_ + ((sl_ ^ (r_ & 3)) * 8)],                \
        (__attribute__((address_space(3))) unsigned int*)&As[buf][r_][sl_ * 8], 16, 0, 0);\
    }                                                                                   \
    {                                                                                   \
      int r_ = tid >> 2, sl_ = tid & 3;                                                 \
      __builtin_amdgcn_global_load_lds(                                                 \
        (const __attribute__((address_space(1))) unsigned int*)                         \
          &BT[(size_t)(colBase + r_) * K + k0_ + ((sl_ ^ (r_ & 3)) * 8)],               \
        (__attribute__((address_space(3))) unsigned int*)&Bs[buf][r_][sl_ * 8], 16, 0, 0);\
    }                                                                                   \
  } while (0)

  PSTAGE(0, 0);
  for (int t = 0; t < nt; ++t) {
    int cur = t & 1;
    if (t + 1 < nt) {
      PSTAGE(cur ^ 1, t + 1);
      asm volatile("s_waitcnt vmcnt(3)" ::: "memory");   // tile t landed (own wave)
    } else {
      asm volatile("s_waitcnt vmcnt(0)" ::: "memory");
    }
    __builtin_amdgcn_s_barrier();                        // all waves' tile t landed
    __builtin_amdgcn_sched_barrier(0);

    bf16x8 af[4], bfr[2];
    #pragma unroll
    for (int mf = 0; mf < 4; ++mf) {
      int row = wm*64 + mf*16 + lr;
      af[mf]  = *(const bf16x8*)&As[cur][row][((lg ^ (lr & 3)) * 8)];
    }
    #pragma unroll
    for (int nf = 0; nf < 2; ++nf) {
      int row = wn*32 + nf*16 + lr;
      bfr[nf] = *(const bf16x8*)&Bs[cur][row][((lg ^ (lr & 3)) * 8)];
    }
    #pragma unroll
    for (int mf = 0; mf < 4; ++mf)
      #pragma unroll
      for (int nf = 0; nf < 2; ++nf)
        acc[mf][nf] = MFMA16(af[mf], bfr[nf], acc[mf][nf]);

    __builtin_amdgcn_s_barrier();                        // readers done before overwrite
  }
#undef PSTAGE

  #pragma unroll
  for (int mf = 0; mf < 4; ++mf)
    #pragma unroll
    for (int nf = 0; nf < 2; ++nf)
      #pragma unroll
      for (int r = 0; r < 4; ++r) {
        int row = rowBase + wm*64 + mf*16 + lg*4 + r;
        int col = colBase + wn*32 + nf*16 + lr;
        C[(size_t)row * N + col] = acc[mf][nf][r];
      }
}

// pack two floats to one dword of 2 bf16 (compiler emits v_cvt_pk_bf16_f32)
__device__ __forceinline__ unsigned pk2(float lo, float hi_) {
  bf16x2 t; t[0] = (__bf16)lo; t[1] = (__bf16)hi_;
  return __builtin_bit_cast(unsigned, t);
}

// ------------- Split-KV flash attention, LDS-shared K/V, 8 waves/block -------------
// Exact R15-proven version (44.7us): 8 waves, grid 640, depth-1 counted-vmcnt
// double-buffer, conflict-free V placement.
__global__ __launch_bounds__(512) void attn_chunk(const __hip_bfloat16* __restrict__ Qb,
                                                  const __hip_bfloat16* __restrict__ Kb,
                                                  const __hip_bfloat16* __restrict__ Vt,
                                                  __hip_bfloat16* __restrict__ Opart,
                                                  float* __restrict__ sbuf) {
  __shared__ __hip_bfloat16 Ks[2][2048];   // [32 kv][8 slots of 8 bf16], swizzled
  __shared__ __hip_bfloat16 Vs[2][2048];   // 256 granules, bank-spread placement
  int tid = threadIdx.x;
  int wid = tid >> 6, lane = tid & 63;
  int ql = lane & 31, hi = lane >> 5;

  int bid = blockIdx.x;
  int bh, c, jbase, lenmax; bool diag;
  if (bid < 384) {                       // full chunks (len 16)
    bh = bid / 12; int pr = bid % 12;
    if (pr < 6)       { c = 0; jbase = 16 + 8*pr; }
    else if (pr < 10) { c = 1; jbase = 32 + 8*(pr-6); }
    else              { c = 2; jbase = 48 + 8*(pr-10); }
    lenmax = 16; diag = false;
  } else {                               // diagonal chunks; longer halves first (LPT)
    int e = bid - 384;
    int hh = (e < 128) ? 1 : 0;
    int e2 = e & 127;
    bh = e2 >> 2; c = e2 & 3;
    jbase = 16*c + 8*hh; lenmax = 8*hh + 8; diag = true;
  }
  int j = jbase + wid;
  int len = diag ? ((j & 15) + 1) : 16;
  int q0 = j * 32, t0 = c * 512;
  int jobid;
  if (!diag) jobid = (c == 0) ? (j - 16) : ((c == 1) ? (j + 16) : (j + 32));
  else       jobid = 96 + ((15 - (j & 15)) << 2) + c;
  int job = jobid * 32 + bh;

  const __hip_bfloat16* Qp = Qb + (size_t)bh * 2048 * 64;
  const __hip_bfloat16* Kp = Kb + (size_t)bh * 2048 * 64;
  const __hip_bfloat16* Vp = Vt + (size_t)bh * 64 * 2048;

  bf16x8 qf[4];
  #pragma unroll
  for (int cc = 0; cc < 4; ++cc)
    qf[cc] = *(const bf16x8*)&Qp[(size_t)(q0 + ql) * 64 + cc*16 + hi*8];

  f32x16 o0, o1;
  #pragma unroll
  for (int r = 0; r < 16; ++r) { o0[r] = 0.f; o1[r] = 0.f; }
  float s = 0.f;

  // staging thread roles (constant across iters)
  int kr = tid >> 3, ksl = tid & 7;                    // threads 0..255: K row/slot
  int vjj = tid - 256;                                 // threads 256..511: V granule L
  int ve  = (vjj >> 4) & 1;
  int vx  = vjj ^ (ve << 2);
  int vr  = vx >> 2;                                   // V source row d
  int vtc = (vx & 3) ^ (vr & 3);                       // V source 16B granule

#define ASTAGE(buf, it_)                                                                \
  do {                                                                                  \
    int kv0_ = t0 + (it_) * 32;                                                         \
    if (tid < 256)                                                                      \
      __builtin_amdgcn_global_load_lds(                                                 \
        (const __attribute__((address_space(1))) unsigned int*)                         \
          &Kp[(size_t)(kv0_ + kr) * 64 + ((ksl ^ (kr & 7)) * 8)],                       \
        (__attribute__((address_space(3))) unsigned int*)&Ks[buf][tid * 8], 16, 0, 0);  \
    else                                                                                \
      __builtin_amdgcn_global_load_lds(                                                 \
        (const __attribute__((address_space(1))) unsigned int*)                         \
          &Vp[(size_t)vr * 2048 + kv0_ + vtc * 8],                                      \
        (__attribute__((address_space(3))) unsigned int*)&Vs[buf][vjj * 8], 16, 0, 0);  \
  } while (0)

  ASTAGE(0, 0);
  for (int it = 0; it < lenmax; ++it) {
    int cur = it & 1;
    if (it + 1 < lenmax) {
      ASTAGE(cur ^ 1, it + 1);
      asm volatile("s_waitcnt vmcnt(1)" ::: "memory");   // tile it landed (own wave)
    } else {
      asm volatile("s_waitcnt vmcnt(0)" ::: "memory");
    }
    __builtin_amdgcn_s_barrier();                        // all waves' tile it landed
    __builtin_amdgcn_sched_barrier(0);

    if (it < len) {
      int kv0 = t0 + it * 32;
      bf16x8 kf[4], vf[4];
      #pragma unroll
      for (int cc = 0; cc < 4; ++cc)
        kf[cc] = *(const bf16x8*)&Ks[cur][ql * 64 + (((cc*2 + hi) ^ (ql & 7)) * 8)];
      #pragma unroll
      for (int g = 0; g < 2; ++g)
        #pragma unroll
        for (int cc = 0; cc < 2; ++cc) {
          int d_ = g*32 + ql, tc_ = cc*2 + hi;
          int L = (d_*4 + (tc_ ^ (d_ & 3))) ^ (((d_ >> 2) & 1) << 2);
          vf[g*2 + cc] = *(const bf16x8*)&Vs[cur][L * 8];
        }

      f32x16 st;
      #pragma unroll
      for (int r = 0; r < 16; ++r) st[r] = 0.f;
      #pragma unroll
      for (int cc = 0; cc < 4; ++cc) st = MFMA32(kf[cc], qf[cc], st);
      // st is in log2 units (Q pre-scaled by 0.125*log2e)

      if (diag && it == len - 1) {       // diagonal tile: causal mask
        #pragma unroll
        for (int r = 0; r < 16; ++r) {
          int kv = kv0 + (r & 3) + 8*(r >> 2) + 4*hi;
          if (kv > q0 + ql) st[r] = -1e30f;
        }
      }

      float p[16]; float ps = 0.f;
      #pragma unroll
      for (int r = 0; r < 16; ++r) { p[r] = exp2f(st[r]); ps += p[r]; }
      ps += __shfl_xor(ps, 32);
      s += ps;

      // P^T B-frag pack: pack own pairs to bf16 dwords, exchange cross-half dwords
      bf16x8 pb[2];
      #pragma unroll
      for (int cc = 0; cc < 2; ++cc) {
        unsigned w0 = pk2(p[cc*8+0], p[cc*8+1]);
        unsigned w1 = pk2(p[cc*8+2], p[cc*8+3]);
        unsigned w2 = pk2(p[cc*8+4], p[cc*8+5]);
        unsigned w3 = pk2(p[cc*8+6], p[cc*8+7]);
        unsigned r0 = __shfl_xor(hi ? w0 : w2, 32);
        unsigned r1 = __shfl_xor(hi ? w1 : w3, 32);
        u32x4 pw;
        pw[0] = hi ? r0 : w0;
        pw[1] = hi ? r1 : w1;
        pw[2] = hi ? w2 : r0;
        pw[3] = hi ? w3 : r1;
        pb[cc] = __builtin_bit_cast(bf16x8, pw);
      }

      o0 = MFMA32(vf[0], pb[0], o0);
      o0 = MFMA32(vf[1], pb[1], o0);
      o1 = MFMA32(vf[2], pb[0], o1);
      o1 = MFMA32(vf[3], pb[1], o1);
    }
    __builtin_amdgcn_s_barrier();                        // readers done before overwrite
  }
#undef ASTAGE

  // write UNNORMALIZED partial: Opart[job][ql][d] (bf16, [32][64] per job), sbuf[job][ql]=s
  __hip_bfloat16* Op = Opart + (size_t)job * 2048 + ql * 64;
  #pragma unroll
  for (int rr = 0; rr < 4; ++rr) {
    bf16x4 w;
    #pragma unroll
    for (int e = 0; e < 4; ++e) w[e] = (__bf16)o0[rr*4 + e];
    *(bf16x4*)&Op[8*rr + 4*hi] = w;
  }
  #pragma unroll
  for (int rr = 0; rr < 4; ++rr) {
    bf16x4 w;
    #pragma unroll
    for (int e = 0; e < 4; ++e) w[e] = (__bf16)o1[rr*4 + e];
    *(bf16x4*)&Op[32 + 8*rr + 4*hi] = w;
  }
  if (hi == 0) sbuf[(size_t)job * 32 + ql] = s;
}

// ------------- combine partials: per (b,h,j) sum <=4 chunks, normalize, write Ob -------------
__global__ __launch_bounds__(64) void attn_combine(const __hip_bfloat16* __restrict__ Opart,
                                                   const float* __restrict__ sbuf,
                                                   __hip_bfloat16* __restrict__ Ob) {
  int bid2 = blockIdx.x;              // 2048 = 64 j x 32 bh
  int j = bid2 >> 5, bh = bid2 & 31;
  int h = bh & 15, b = bh >> 4;
  int tid = threadIdx.x, ql = tid & 31, half = tid >> 5;
  int nc = (j >> 4) + 1;

  int gs[4];
  const int Sseg[3] = {0, 48, 80};
  #pragma unroll
  for (int i = 0; i < 3; ++i)
    if (i < nc - 1) gs[i] = (Sseg[i] + j - 16*(i+1)) * 32 + bh;
  gs[nc-1] = (96 + 4*(15 - (j & 15)) + (j >> 4)) * 32 + bh;

  float Ssum = 0.f;
  #pragma unroll
  for (int i = 0; i < 4; ++i)
    if (i < nc) Ssum += sbuf[(size_t)gs[i]*32 + ql];

  float acc[32];
  #pragma unroll
  for (int e = 0; e < 32; ++e) acc[e] = 0.f;
  #pragma unroll
  for (int i = 0; i < 4; ++i)
    if (i < nc) {
      const bf16x8* src = (const bf16x8*)(Opart + (size_t)gs[i]*2048 + ql*64 + half*32);
      #pragma unroll
      for (int q4 = 0; q4 < 4; ++q4) {
        bf16x8 v = src[q4];
        #pragma unroll
        for (int e = 0; e < 8; ++e) acc[q4*8 + e] += (float)v[e];
      }
    }

  float inv = 1.f / Ssum;
  size_t row = (size_t)b * 2048 + j*32 + ql;
  __hip_bfloat16* dst = Ob + row * 1024 + h*64 + half*32;
  #pragma unroll
  for (int q4 = 0; q4 < 4; ++q4) {
    bf16x8 w;
    #pragma unroll
    for (int e = 0; e < 8; ++e) w[e] = (__bf16)(acc[q4*8 + e] * inv);
    *(bf16x8*)&dst[q4*8] = w;
  }
}

// ---------------------------------------------------------------------------
extern "C" void kernel_launch(void* const* d_in, const int* in_sizes, int n_in,
                              void* d_out, int out_size, void* d_ws, size_t ws_size,
                              hipStream_t stream) {
  const float* x     = (const float*)d_in[0];
  // d_in[1] = mask (fixed causal triu) — implemented analytically
  const float* Wqkv  = (const float*)d_in[2];
  const float* Wproj = (const float*)d_in[3];
  float* out = (float*)d_out;

  char* ws = (char*)d_ws;
  const size_t MB = 1024 * 1024;
  __hip_bfloat16* xb  = (__hip_bfloat16*)(ws);            //  8 MB  [4096][1024]
  __hip_bfloat16* Wqt = (__hip_bfloat16*)(ws +  8*MB);    //  6 MB  [3072][1024]
  __hip_bfloat16* Wpt = (__hip_bfloat16*)(ws + 14*MB);    //  2 MB  [1024][1024]
  __hip_bfloat16* Qb  = (__hip_bfloat16*)(ws + 40*MB);    //  8 MB  [B,H,T,64]
  __hip_bfloat16* Kb  = (__hip_bfloat16*)(ws + 48*MB);    //  8 MB
  __hip_bfloat16* Vt  = (__hip_bfloat16*)(ws + 56*MB);    //  8 MB  [B,H,64,T]
  __hip_bfloat16* Ob  = (__hip_bfloat16*)(ws + 64*MB);    //  8 MB  [4096][1024]
  __hip_bfloat16* Opart = (__hip_bfloat16*)(ws + 16*MB);  // 20 MB  [5120][32][64]
  float*          sbuf  = (float*)(ws + 36*MB);           // 640KB  [5120][32]
  float2*         sctbl = (float2*)(ws + 37*MB);          // 512KB  [2048*32]

  cast_f32_bf16<<<4096, 256, 0, stream>>>(x, xb, 1048576);
  transpose_cast<<<dim3(96, 32), 256, 0, stream>>>(Wqkv, Wqt, 1024, 3072);
  transpose_cast<<<dim3(32, 32), 256, 0, stream>>>(Wproj, Wpt, 1024, 1024);
  build_sincos<<<256, 256, 0, stream>>>(sctbl);
  gemm_qkv<<<dim3(24, 32), 256, 0, stream>>>(xb, Wqt, sctbl, Qb, Kb, Vt);
  attn_chunk<<<640, 512, 0, stream>>>(Qb, Kb, Vt, Opart, sbuf);
  attn_combine<<<2048, 64, 0, stream>>>(Opart, sbuf, Ob);
  gemm_proj<<<dim3(16, 32), 256, 0, stream>>>(Ob, Wpt, out, 4096, 1024, 1024);
}

// Round 24
// 114.898 us; speedup vs baseline: 1.2437x; 1.0501x over previous
//
#include <hip/hip_runtime.h>
#include <hip/hip_bf16.h>

typedef __bf16  bf16x8 __attribute__((ext_vector_type(8)));
typedef __bf16  bf16x4 __attribute__((ext_vector_type(4)));
typedef __bf16  bf16x2 __attribute__((ext_vector_type(2)));
typedef float   f32x4  __attribute__((ext_vector_type(4)));
typedef float   f32x16 __attribute__((ext_vector_type(16)));
typedef unsigned u32x4 __attribute__((ext_vector_type(4)));

#define MFMA16(a,b,c) __builtin_amdgcn_mfma_f32_16x16x32_bf16(a,b,c,0,0,0)
#define MFMA32(a,b,c) __builtin_amdgcn_mfma_f32_32x32x16_bf16(a,b,c,0,0,0)

// B=2, T=2048, D=1024, H=16, Dh=64

struct bf4 { __hip_bfloat16 a,b,c,d; };

// ------------- fused prep: cast x, transpose Wqkv, transpose Wproj, sincos table ------
// Block ranges: [0,4096) cast | [4096,7168) Wqkv T | [7168,8192) Wproj T | [8192,8448) tbl
__global__ __launch_bounds__(256) void prep(const float* __restrict__ x,
                                            const float* __restrict__ Wqkv,
                                            const float* __restrict__ Wproj,
                                            __hip_bfloat16* __restrict__ xb,
                                            __hip_bfloat16* __restrict__ Wqt,
                                            __hip_bfloat16* __restrict__ Wpt,
                                            float2* __restrict__ tbl) {
  __shared__ float tile[32][33];
  int bid = blockIdx.x;
  if (bid < 4096) {
    // cast x (fp32 -> bf16), 4 elems/thread
    int i = bid * 256 + threadIdx.x;
    float4 v = ((const float4*)x)[i];
    bf4 o { __float2bfloat16(v.x), __float2bfloat16(v.y),
            __float2bfloat16(v.z), __float2bfloat16(v.w) };
    ((bf4*)xb)[i] = o;
  } else if (bid < 8192) {
    // transpose + cast: W[R][C] fp32 -> WT[C][R] bf16
    const float* W; __hip_bfloat16* WT; int R, C, bx, by;
    if (bid < 7168) { int e = bid - 4096; W = Wqkv;  WT = Wqt; R = 1024; C = 3072; bx = e % 96; by = e / 96; }
    else            { int e = bid - 7168; W = Wproj; WT = Wpt; R = 1024; C = 1024; bx = e % 32; by = e / 32; }
    int c0 = bx * 32, r0 = by * 32;
    int tx = threadIdx.x & 31, ty = threadIdx.x >> 5;   // 32 x 8
    #pragma unroll
    for (int i = 0; i < 32; i += 8)
      tile[ty + i][tx] = W[(size_t)(r0 + ty + i) * C + c0 + tx];
    __syncthreads();
    #pragma unroll
    for (int i = 0; i < 32; i += 8)
      WT[(size_t)(c0 + ty + i) * R + r0 + tx] = __float2bfloat16(tile[tx][ty + i]);
  } else {
    // sincos table: tbl[t*32+i] = {sin,cos}(t * 10000^(-i/32))
    int idx = (bid - 8192) * 256 + threadIdx.x;   // 65536 = 2048 t x 32 i
    int i = idx & 31, t = idx >> 5;
    float theta = expf(-9.210340371976184f * (float)i * 0.03125f);
    float sn, cs;
    sincosf((float)t * theta, &sn, &cs);
    tbl[idx] = float2{sn, cs};
  }
}

// ------------- fused QKV GEMM: qkv = xb @ WqtT, epilogue does RoPE + reorg -------------
// Main loop = R10/R15-proven 128x128 BK=32 double-buffered counted-vmcnt pipeline.
// Epilogue by column region (uniform per block, since 1024 % 128 == 0):
//   region 0 (Q): RoPE rotate in-register, scale by QS, write Qb
//   region 1 (K): RoPE rotate, write Kb
//   region 2 (V): transpose 128t x 128d through LDS, write Vt
__global__ __launch_bounds__(256) void gemm_qkv(const __hip_bfloat16* __restrict__ A,
                                                const __hip_bfloat16* __restrict__ BT,
                                                const float2* __restrict__ tbl,
                                                __hip_bfloat16* __restrict__ Qb,
                                                __hip_bfloat16* __restrict__ Kb,
                                                __hip_bfloat16* __restrict__ Vt) {
  __shared__ __align__(16) char smem[34816];   // max(As+Bs = 32KB, Vl = 128*136*2)
  auto As = (__hip_bfloat16 (*)[128][32])(smem);
  auto Bs = (__hip_bfloat16 (*)[128][32])(smem + 16384);
  auto Vl = (__hip_bfloat16 (*)[136])(smem);
  const int K = 1024;
  int tid  = threadIdx.x;
  int lane = tid & 63, wid = tid >> 6;
  int wm = wid >> 1, wn = wid & 1;
  int rowBase = blockIdx.y * 128;
  int colBase = blockIdx.x * 128;
  int lr = lane & 15, lg = lane >> 4;

  f32x4 acc[4][4];
  #pragma unroll
  for (int i = 0; i < 4; ++i)
    #pragma unroll
    for (int j = 0; j < 4; ++j) acc[i][j] = f32x4{0.f,0.f,0.f,0.f};

  int nt = K >> 5;

#define GSTAGE(buf, kt)                                                                 \
  do {                                                                                  \
    int k0_ = (kt) << 5;                                                                \
    _Pragma("unroll")                                                                   \
    for (int p = 0; p < 2; ++p) {                                                       \
      int idx = p * 256 + tid;                                                          \
      int r_ = idx >> 2, sl_ = idx & 3;                                                 \
      __builtin_amdgcn_global_load_lds(                                                 \
        (const __attribute__((address_space(1))) unsigned int*)                         \
          &A[(size_t)(rowBase + r_) * K + k0_ + ((sl_ ^ (r_ & 3)) * 8)],                \
        (__attribute__((address_space(3))) unsigned int*)&As[buf][r_][sl_ * 8], 16, 0, 0);\
      __builtin_amdgcn_global_load_lds(                                                 \
        (const __attribute__((address_space(1))) unsigned int*)                         \
          &BT[(size_t)(colBase + r_) * K + k0_ + ((sl_ ^ (r_ & 3)) * 8)],               \
        (__attribute__((address_space(3))) unsigned int*)&Bs[buf][r_][sl_ * 8], 16, 0, 0);\
    }                                                                                   \
  } while (0)

  GSTAGE(0, 0);
  for (int t = 0; t < nt; ++t) {
    int cur = t & 1;
    if (t + 1 < nt) {
      GSTAGE(cur ^ 1, t + 1);
      asm volatile("s_waitcnt vmcnt(4)" ::: "memory");   // tile t landed (own wave)
    } else {
      asm volatile("s_waitcnt vmcnt(0)" ::: "memory");
    }
    __builtin_amdgcn_s_barrier();                        // all waves' tile t landed
    __builtin_amdgcn_sched_barrier(0);

    bf16x8 af[4], bfr[4];
    #pragma unroll
    for (int mf = 0; mf < 4; ++mf) {
      int row = wm*64 + mf*16 + lr;
      af[mf]  = *(const bf16x8*)&As[cur][row][((lg ^ (lr & 3)) * 8)];
    }
    #pragma unroll
    for (int nf = 0; nf < 4; ++nf) {
      int row = wn*64 + nf*16 + lr;
      bfr[nf] = *(const bf16x8*)&Bs[cur][row][((lg ^ (lr & 3)) * 8)];
    }
    #pragma unroll
    for (int mf = 0; mf < 4; ++mf)
      #pragma unroll
      for (int nf = 0; nf < 4; ++nf)
        acc[mf][nf] = MFMA16(af[mf], bfr[nf], acc[mf][nf]);

    __builtin_amdgcn_s_barrier();                        // readers done before overwrite
  }
#undef GSTAGE

  int region = colBase >> 10;                  // 0=Q, 1=K, 2=V
  int b = rowBase >> 11;
  if (region < 2) {
    const float QS = 0.18033688011112042f;     // (1/8) * log2(e)
    __hip_bfloat16* dst = (region == 0) ? Qb : Kb;
    float scale = (region == 0) ? QS : 1.0f;
    int h = ((colBase & 1023) >> 6) + wn;
    #pragma unroll
    for (int mf = 0; mf < 4; ++mf)
      #pragma unroll
      for (int r = 0; r < 4; ++r) {
        int row = rowBase + wm*64 + mf*16 + lg*4 + r;
        int t = row & 2047;
        #pragma unroll
        for (int nf = 0; nf < 2; ++nf) {
          int i = nf*16 + lr;                  // 0..31
          float2 sc = tbl[(t << 5) + i];
          float v1 = acc[mf][nf][r], v2 = acc[mf][nf+2][r];
          size_t base = ((size_t)((b*16 + h) * 2048 + t)) * 64;
          dst[base + i]      = __float2bfloat16(( v1*sc.y + v2*sc.x) * scale);
          dst[base + 32 + i] = __float2bfloat16((-v1*sc.x + v2*sc.y) * scale);
        }
      }
  } else {
    // V: stage acc into LDS d-major, then coalesced-ish copy-out transposed
    #pragma unroll
    for (int nf = 0; nf < 4; ++nf) {
      int d = wn*64 + nf*16 + lr;
      #pragma unroll
      for (int mf = 0; mf < 4; ++mf) {
        bf16x4 w;
        #pragma unroll
        for (int r = 0; r < 4; ++r) w[r] = (__bf16)acc[mf][nf][r];
        *(bf16x4*)&Vl[d][wm*64 + mf*16 + lg*4] = w;
      }
    }
    __syncthreads();
    int vd = tid >> 1, half = tid & 1;
    int h = ((colBase - 2048) >> 6) + (vd >> 6);
    int dloc = vd & 63;
    __hip_bfloat16* dstp = Vt + ((size_t)(b*16 + h) * 64 + dloc) * 2048
                              + (rowBase & 2047) + half*64;
    const __hip_bfloat16* srcp = &Vl[vd][half*64];
    #pragma unroll
    for (int g = 0; g < 8; ++g)
      *(bf16x8*)&dstp[g*8] = *(const bf16x8*)&srcp[g*8];
  }
}

// ------------- proj GEMM: C[M][N] = A[M][K] * BT[N][K]^T, fp32 out -------------
// 128x64 tile (512 blocks = 2 blocks/CU), BK=32, double-buffered counted-vmcnt
// pipeline (3 loads/thread -> vmcnt(3)). Waves 2x2, each owning 64x32 (acc[4][2]).
__global__ __launch_bounds__(256) void gemm_proj(const __hip_bfloat16* __restrict__ A,
                                                 const __hip_bfloat16* __restrict__ BT,
                                                 float* __restrict__ C,
                                                 int M, int N, int K) {
  __shared__ __hip_bfloat16 As[2][128][32];
  __shared__ __hip_bfloat16 Bs[2][64][32];
  int tid  = threadIdx.x;
  int lane = tid & 63, wid = tid >> 6;
  int wm = wid >> 1, wn = wid & 1;
  int rowBase = blockIdx.y * 128;
  int colBase = blockIdx.x * 64;
  int lr = lane & 15, lg = lane >> 4;

  f32x4 acc[4][2];
  #pragma unroll
  for (int i = 0; i < 4; ++i)
    #pragma unroll
    for (int j = 0; j < 2; ++j) acc[i][j] = f32x4{0.f,0.f,0.f,0.f};

  int nt = K >> 5;

#define PSTAGE(buf, kt)                                                                 \
  do {                                                                                  \
    int k0_ = (kt) << 5;                                                                \
    _Pragma("unroll")                                                                   \
    for (int p = 0; p < 2; ++p) {                                                       \
      int idx = p * 256 + tid;                                                          \
      int r_ = idx >> 2, sl_ = idx & 3;                                                 \
      __builtin_amdgcn_global_load_lds(                                                 \
        (const __attribute__((address_space(1))) unsigned int*)                         \
          &A[(size_t)(rowBase + r_) * K + k0_ + ((sl_ ^ (r_ & 3)) * 8)],                \
        (__attribute__((address_space(3))) unsigned int*)&As[buf][r_][sl_ * 8], 16, 0, 0);\
    }                                                                                   \
    {                                                                                   \
      int r_ = tid >> 2, sl_ = tid & 3;                                                 \
      __builtin_amdgcn_global_load_lds(                                                 \
        (const __attribute__((address_space(1))) unsigned int*)                         \
          &BT[(size_t)(colBase + r_) * K + k0_ + ((sl_ ^ (r_ & 3)) * 8)],               \
        (__attribute__((address_space(3))) unsigned int*)&Bs[buf][r_][sl_ * 8], 16, 0, 0);\
    }                                                                                   \
  } while (0)

  PSTAGE(0, 0);
  for (int t = 0; t < nt; ++t) {
    int cur = t & 1;
    if (t + 1 < nt) {
      PSTAGE(cur ^ 1, t + 1);
      asm volatile("s_waitcnt vmcnt(3)" ::: "memory");   // tile t landed (own wave)
    } else {
      asm volatile("s_waitcnt vmcnt(0)" ::: "memory");
    }
    __builtin_amdgcn_s_barrier();                        // all waves' tile t landed
    __builtin_amdgcn_sched_barrier(0);

    bf16x8 af[4], bfr[2];
    #pragma unroll
    for (int mf = 0; mf < 4; ++mf) {
      int row = wm*64 + mf*16 + lr;
      af[mf]  = *(const bf16x8*)&As[cur][row][((lg ^ (lr & 3)) * 8)];
    }
    #pragma unroll
    for (int nf = 0; nf < 2; ++nf) {
      int row = wn*32 + nf*16 + lr;
      bfr[nf] = *(const bf16x8*)&Bs[cur][row][((lg ^ (lr & 3)) * 8)];
    }
    #pragma unroll
    for (int mf = 0; mf < 4; ++mf)
      #pragma unroll
      for (int nf = 0; nf < 2; ++nf)
        acc[mf][nf] = MFMA16(af[mf], bfr[nf], acc[mf][nf]);

    __builtin_amdgcn_s_barrier();                        // readers done before overwrite
  }
#undef PSTAGE

  #pragma unroll
  for (int mf = 0; mf < 4; ++mf)
    #pragma unroll
    for (int nf = 0; nf < 2; ++nf)
      #pragma unroll
      for (int r = 0; r < 4; ++r) {
        int row = rowBase + wm*64 + mf*16 + lg*4 + r;
        int col = colBase + wn*32 + nf*16 + lr;
        C[(size_t)row * N + col] = acc[mf][nf][r];
      }
}

// pack two floats to one dword of 2 bf16 (compiler emits v_cvt_pk_bf16_f32)
__device__ __forceinline__ unsigned pk2(float lo, float hi_) {
  bf16x2 t; t[0] = (__bf16)lo; t[1] = (__bf16)hi_;
  return __builtin_bit_cast(unsigned, t);
}

// ------------- Split-KV flash attention, LDS-shared K/V, 8 waves/block -------------
// Exact R15-proven version (44.7us): 8 waves, grid 640, depth-1 counted-vmcnt
// double-buffer, conflict-free V placement.
__global__ __launch_bounds__(512) void attn_chunk(const __hip_bfloat16* __restrict__ Qb,
                                                  const __hip_bfloat16* __restrict__ Kb,
                                                  const __hip_bfloat16* __restrict__ Vt,
                                                  __hip_bfloat16* __restrict__ Opart,
                                                  float* __restrict__ sbuf) {
  __shared__ __hip_bfloat16 Ks[2][2048];   // [32 kv][8 slots of 8 bf16], swizzled
  __shared__ __hip_bfloat16 Vs[2][2048];   // 256 granules, bank-spread placement
  int tid = threadIdx.x;
  int wid = tid >> 6, lane = tid & 63;
  int ql = lane & 31, hi = lane >> 5;

  int bid = blockIdx.x;
  int bh, c, jbase, lenmax; bool diag;
  if (bid < 384) {                       // full chunks (len 16)
    bh = bid / 12; int pr = bid % 12;
    if (pr < 6)       { c = 0; jbase = 16 + 8*pr; }
    else if (pr < 10) { c = 1; jbase = 32 + 8*(pr-6); }
    else              { c = 2; jbase = 48 + 8*(pr-10); }
    lenmax = 16; diag = false;
  } else {                               // diagonal chunks; longer halves first (LPT)
    int e = bid - 384;
    int hh = (e < 128) ? 1 : 0;
    int e2 = e & 127;
    bh = e2 >> 2; c = e2 & 3;
    jbase = 16*c + 8*hh; lenmax = 8*hh + 8; diag = true;
  }
  int j = jbase + wid;
  int len = diag ? ((j & 15) + 1) : 16;
  int q0 = j * 32, t0 = c * 512;
  int jobid;
  if (!diag) jobid = (c == 0) ? (j - 16) : ((c == 1) ? (j + 16) : (j + 32));
  else       jobid = 96 + ((15 - (j & 15)) << 2) + c;
  int job = jobid * 32 + bh;

  const __hip_bfloat16* Qp = Qb + (size_t)bh * 2048 * 64;
  const __hip_bfloat16* Kp = Kb + (size_t)bh * 2048 * 64;
  const __hip_bfloat16* Vp = Vt + (size_t)bh * 64 * 2048;

  bf16x8 qf[4];
  #pragma unroll
  for (int cc = 0; cc < 4; ++cc)
    qf[cc] = *(const bf16x8*)&Qp[(size_t)(q0 + ql) * 64 + cc*16 + hi*8];

  f32x16 o0, o1;
  #pragma unroll
  for (int r = 0; r < 16; ++r) { o0[r] = 0.f; o1[r] = 0.f; }
  float s = 0.f;

  // staging thread roles (constant across iters)
  int kr = tid >> 3, ksl = tid & 7;                    // threads 0..255: K row/slot
  int vjj = tid - 256;                                 // threads 256..511: V granule L
  int ve  = (vjj >> 4) & 1;
  int vx  = vjj ^ (ve << 2);
  int vr  = vx >> 2;                                   // V source row d
  int vtc = (vx & 3) ^ (vr & 3);                       // V source 16B granule

#define ASTAGE(buf, it_)                                                                \
  do {                                                                                  \
    int kv0_ = t0 + (it_) * 32;                                                         \
    if (tid < 256)                                                                      \
      __builtin_amdgcn_global_load_lds(                                                 \
        (const __attribute__((address_space(1))) unsigned int*)                         \
          &Kp[(size_t)(kv0_ + kr) * 64 + ((ksl ^ (kr & 7)) * 8)],                       \
        (__attribute__((address_space(3))) unsigned int*)&Ks[buf][tid * 8], 16, 0, 0);  \
    else                                                                                \
      __builtin_amdgcn_global_load_lds(                                                 \
        (const __attribute__((address_space(1))) unsigned int*)                         \
          &Vp[(size_t)vr * 2048 + kv0_ + vtc * 8],                                      \
        (__attribute__((address_space(3))) unsigned int*)&Vs[buf][vjj * 8], 16, 0, 0);  \
  } while (0)

  ASTAGE(0, 0);
  for (int it = 0; it < lenmax; ++it) {
    int cur = it & 1;
    if (it + 1 < lenmax) {
      ASTAGE(cur ^ 1, it + 1);
      asm volatile("s_waitcnt vmcnt(1)" ::: "memory");   // tile it landed (own wave)
    } else {
      asm volatile("s_waitcnt vmcnt(0)" ::: "memory");
    }
    __builtin_amdgcn_s_barrier();                        // all waves' tile it landed
    __builtin_amdgcn_sched_barrier(0);

    if (it < len) {
      int kv0 = t0 + it * 32;
      bf16x8 kf[4], vf[4];
      #pragma unroll
      for (int cc = 0; cc < 4; ++cc)
        kf[cc] = *(const bf16x8*)&Ks[cur][ql * 64 + (((cc*2 + hi) ^ (ql & 7)) * 8)];
      #pragma unroll
      for (int g = 0; g < 2; ++g)
        #pragma unroll
        for (int cc = 0; cc < 2; ++cc) {
          int d_ = g*32 + ql, tc_ = cc*2 + hi;
          int L = (d_*4 + (tc_ ^ (d_ & 3))) ^ (((d_ >> 2) & 1) << 2);
          vf[g*2 + cc] = *(const bf16x8*)&Vs[cur][L * 8];
        }

      f32x16 st;
      #pragma unroll
      for (int r = 0; r < 16; ++r) st[r] = 0.f;
      #pragma unroll
      for (int cc = 0; cc < 4; ++cc) st = MFMA32(kf[cc], qf[cc], st);
      // st is in log2 units (Q pre-scaled by 0.125*log2e)

      if (diag && it == len - 1) {       // diagonal tile: causal mask
        #pragma unroll
        for (int r = 0; r < 16; ++r) {
          int kv = kv0 + (r & 3) + 8*(r >> 2) + 4*hi;
          if (kv > q0 + ql) st[r] = -1e30f;
        }
      }

      float p[16]; float ps = 0.f;
      #pragma unroll
      for (int r = 0; r < 16; ++r) { p[r] = exp2f(st[r]); ps += p[r]; }
      ps += __shfl_xor(ps, 32);
      s += ps;

      // P^T B-frag pack: pack own pairs to bf16 dwords, exchange cross-half dwords
      bf16x8 pb[2];
      #pragma unroll
      for (int cc = 0; cc < 2; ++cc) {
        unsigned w0 = pk2(p[cc*8+0], p[cc*8+1]);
        unsigned w1 = pk2(p[cc*8+2], p[cc*8+3]);
        unsigned w2 = pk2(p[cc*8+4], p[cc*8+5]);
        unsigned w3 = pk2(p[cc*8+6], p[cc*8+7]);
        unsigned r0 = __shfl_xor(hi ? w0 : w2, 32);
        unsigned r1 = __shfl_xor(hi ? w1 : w3, 32);
        u32x4 pw;
        pw[0] = hi ? r0 : w0;
        pw[1] = hi ? r1 : w1;
        pw[2] = hi ? w2 : r0;
        pw[3] = hi ? w3 : r1;
        pb[cc] = __builtin_bit_cast(bf16x8, pw);
      }

      o0 = MFMA32(vf[0], pb[0], o0);
      o0 = MFMA32(vf[1], pb[1], o0);
      o1 = MFMA32(vf[2], pb[0], o1);
      o1 = MFMA32(vf[3], pb[1], o1);
    }
    __builtin_amdgcn_s_barrier();                        // readers done before overwrite
  }
#undef ASTAGE

  // write UNNORMALIZED partial: Opart[job][ql][d] (bf16, [32][64] per job), sbuf[job][ql]=s
  __hip_bfloat16* Op = Opart + (size_t)job * 2048 + ql * 64;
  #pragma unroll
  for (int rr = 0; rr < 4; ++rr) {
    bf16x4 w;
    #pragma unroll
    for (int e = 0; e < 4; ++e) w[e] = (__bf16)o0[rr*4 + e];
    *(bf16x4*)&Op[8*rr + 4*hi] = w;
  }
  #pragma unroll
  for (int rr = 0; rr < 4; ++rr) {
    bf16x4 w;
    #pragma unroll
    for (int e = 0; e < 4; ++e) w[e] = (__bf16)o1[rr*4 + e];
    *(bf16x4*)&Op[32 + 8*rr + 4*hi] = w;
  }
  if (hi == 0) sbuf[(size_t)job * 32 + ql] = s;
}

// ------------- combine partials: per (b,h,j) sum <=4 chunks, normalize, write Ob -------------
__global__ __launch_bounds__(64) void attn_combine(const __hip_bfloat16* __restrict__ Opart,
                                                   const float* __restrict__ sbuf,
                                                   __hip_bfloat16* __restrict__ Ob) {
  int bid2 = blockIdx.x;              // 2048 = 64 j x 32 bh
  int j = bid2 >> 5, bh = bid2 & 31;
  int h = bh & 15, b = bh >> 4;
  int tid = threadIdx.x, ql = tid & 31, half = tid >> 5;
  int nc = (j >> 4) + 1;

  int gs[4];
  const int Sseg[3] = {0, 48, 80};
  #pragma unroll
  for (int i = 0; i < 3; ++i)
    if (i < nc - 1) gs[i] = (Sseg[i] + j - 16*(i+1)) * 32 + bh;
  gs[nc-1] = (96 + 4*(15 - (j & 15)) + (j >> 4)) * 32 + bh;

  float Ssum = 0.f;
  #pragma unroll
  for (int i = 0; i < 4; ++i)
    if (i < nc) Ssum += sbuf[(size_t)gs[i]*32 + ql];

  float acc[32];
  #pragma unroll
  for (int e = 0; e < 32; ++e) acc[e] = 0.f;
  #pragma unroll
  for (int i = 0; i < 4; ++i)
    if (i < nc) {
      const bf16x8* src = (const bf16x8*)(Opart + (size_t)gs[i]*2048 + ql*64 + half*32);
      #pragma unroll
      for (int q4 = 0; q4 < 4; ++q4) {
        bf16x8 v = src[q4];
        #pragma unroll
        for (int e = 0; e < 8; ++e) acc[q4*8 + e] += (float)v[e];
      }
    }

  float inv = 1.f / Ssum;
  size_t row = (size_t)b * 2048 + j*32 + ql;
  __hip_bfloat16* dst = Ob + row * 1024 + h*64 + half*32;
  #pragma unroll
  for (int q4 = 0; q4 < 4; ++q4) {
    bf16x8 w;
    #pragma unroll
    for (int e = 0; e < 8; ++e) w[e] = (__bf16)(acc[q4*8 + e] * inv);
    *(bf16x8*)&dst[q4*8] = w;
  }
}

// ---------------------------------------------------------------------------
extern "C" void kernel_launch(void* const* d_in, const int* in_sizes, int n_in,
                              void* d_out, int out_size, void* d_ws, size_t ws_size,
                              hipStream_t stream) {
  const float* x     = (const float*)d_in[0];
  // d_in[1] = mask (fixed causal triu) — implemented analytically
  const float* Wqkv  = (const float*)d_in[2];
  const float* Wproj = (const float*)d_in[3];
  float* out = (float*)d_out;

  char* ws = (char*)d_ws;
  const size_t MB = 1024 * 1024;
  __hip_bfloat16* xb  = (__hip_bfloat16*)(ws);            //  8 MB  [4096][1024]
  __hip_bfloat16* Wqt = (__hip_bfloat16*)(ws +  8*MB);    //  6 MB  [3072][1024]
  __hip_bfloat16* Wpt = (__hip_bfloat16*)(ws + 14*MB);    //  2 MB  [1024][1024]
  __hip_bfloat16* Qb  = (__hip_bfloat16*)(ws + 40*MB);    //  8 MB  [B,H,T,64]
  __hip_bfloat16* Kb  = (__hip_bfloat16*)(ws + 48*MB);    //  8 MB
  __hip_bfloat16* Vt  = (__hip_bfloat16*)(ws + 56*MB);    //  8 MB  [B,H,64,T]
  __hip_bfloat16* Ob  = (__hip_bfloat16*)(ws + 64*MB);    //  8 MB  [4096][1024]
  __hip_bfloat16* Opart = (__hip_bfloat16*)(ws + 16*MB);  // 20 MB  [5120][32][64]
  float*          sbuf  = (float*)(ws + 36*MB);           // 640KB  [5120][32]
  float2*         sctbl = (float2*)(ws + 37*MB);          // 512KB  [2048*32]

  prep<<<8448, 256, 0, stream>>>(x, Wqkv, Wproj, xb, Wqt, Wpt, sctbl);
  gemm_qkv<<<dim3(24, 32), 256, 0, stream>>>(xb, Wqt, sctbl, Qb, Kb, Vt);
  attn_chunk<<<640, 512, 0, stream>>>(Qb, Kb, Vt, Opart, sbuf);
  attn_combine<<<2048, 64, 0, stream>>>(Opart, sbuf, Ob);
  gemm_proj<<<dim3(16, 32), 256, 0, stream>>>(Ob, Wpt, out, 4096, 1024, 1024);
}